// Round 9
// baseline (147.944 us; speedup 1.0000x reference)
//
#include <hip/hip_runtime.h>

// Workspace layout (40 MB total):
//   [0,  8M)  Xb  bf16 [4096][1024]   (reused as Yb after QKV GEMM)
//   [8, 14M)  Wkqv_t bf16 [3072][1024]
//   [14,16M)  Wproj_t bf16 [1024][1024]
//   [16,24M)  Qb bf16 [B,H,T,D]  (pre-scaled by 0.125*log2e)
//   [24,32M)  Kb bf16 [B,H,T,D]
//   [32,40M)  Vb bf16 [B,H,T,D]

#define DEVI __device__ __forceinline__

typedef unsigned short ushort_t;
typedef unsigned long long u64_t;
typedef __attribute__((ext_vector_type(4))) unsigned short us4;
typedef __attribute__((ext_vector_type(8))) unsigned short ushort8;
typedef __attribute__((ext_vector_type(4))) float f32x4;
typedef __attribute__((ext_vector_type(8))) __bf16 bf16x8;

DEVI unsigned short f2bf(float f) {
  union { float f; unsigned int u; } c; c.f = f;
  unsigned int u = c.u;
  unsigned int r = (u + 0x7FFFu + ((u >> 16) & 1u)) >> 16;
  return (unsigned short)r;
}

// exp2 via raw v_exp_f32 (1 VALU trans op; s_nop covers the RAW hazard)
DEVI float exp2v(float x) {
  float r;
  asm("v_exp_f32 %0, %1\n\ts_nop 0" : "=v"(r) : "v"(x));
  return r;
}

// pack 2 fp32 -> 2 bf16 (RNE) in one instruction
DEVI unsigned int cvtpk(float lo, float hi) {
  unsigned int r;
  asm("v_cvt_pk_bf16_f32 %0, %1, %2" : "=v"(r) : "v"(lo), "v"(hi));
  return r;
}

DEVI f32x4 mfma16(ushort8 a, ushort8 b, f32x4 c) {
  return __builtin_amdgcn_mfma_f32_16x16x32_bf16(
      __builtin_bit_cast(bf16x8, a), __builtin_bit_cast(bf16x8, b), c, 0, 0, 0);
}

typedef const __attribute__((address_space(1))) void* gptr_t;
typedef __attribute__((address_space(3))) void* lptr_t;
#define GLOAD_LDS16(g, l) \
  __builtin_amdgcn_global_load_lds((gptr_t)(g), (lptr_t)(l), 16, 0, 0)

DEVI void bar() {
  asm volatile("" ::: "memory");
  __builtin_amdgcn_s_barrier();
  asm volatile("" ::: "memory");
}
#define VMCNT(n) asm volatile("s_waitcnt vmcnt(" #n ")" ::: "memory")

// ---------------- prep kernels ----------------

__global__ void cast_x_kernel(const float* __restrict__ in,
                              ushort_t* __restrict__ out, int n8) {
  int i = blockIdx.x * blockDim.x + threadIdx.x;
  if (i >= n8) return;
  const f32x4* p = (const f32x4*)in;
  f32x4 a = p[2 * i], b = p[2 * i + 1];
  ushort8 o;
  o[0] = f2bf(a[0]); o[1] = f2bf(a[1]); o[2] = f2bf(a[2]); o[3] = f2bf(a[3]);
  o[4] = f2bf(b[0]); o[5] = f2bf(b[1]); o[6] = f2bf(b[2]); o[7] = f2bf(b[3]);
  ((ushort8*)out)[i] = o;
}

// out[c][r] = bf16(in[r][c]); in is [R][Cin], out is [Cin][R]
__global__ void transpose_cast_kernel(const float* __restrict__ in,
                                      ushort_t* __restrict__ out, int R, int Cin) {
  __shared__ float tile[32][33];
  int c0 = blockIdx.x * 32, r0 = blockIdx.y * 32;
  int tx = threadIdx.x & 31, ty = threadIdx.x >> 5;
#pragma unroll
  for (int it = 0; it < 4; ++it)
    tile[ty + it * 8][tx] = in[(size_t)(r0 + ty + it * 8) * Cin + c0 + tx];
  __syncthreads();
#pragma unroll
  for (int it = 0; it < 4; ++it)
    out[(size_t)(c0 + ty + it * 8) * R + r0 + tx] = f2bf(tile[tx][ty + it * 8]);
}

// ---------------- GEMM: C = A[M,K] * Bt[N,K]^T + bias ----------------
// mode 0: write fp32 out[M][N]
// mode 1: QKV epilogue (scatter q/k/v; Qb pre-scaled by 0.125*log2e for attn)
// m97 structure: 128x128 tile, BK=64, SINGLE-buffered LDS (32 KB), 2
// barriers/kt, conflict-free XOR swizzle, XCD swizzle.

__global__ __launch_bounds__(256) void gemm_bt_kernel(
    const ushort_t* __restrict__ A, const ushort_t* __restrict__ Bt,
    const float* __restrict__ bias, float* __restrict__ outF,
    float* __restrict__ outK, float* __restrict__ outV,
    ushort_t* __restrict__ Qb, ushort_t* __restrict__ Kb, ushort_t* __restrict__ Vb,
    int M, int N, int K, int mode) {
  __shared__ __align__(16) ushort_t As[128 * 64];
  __shared__ __align__(16) ushort_t Bs[128 * 64];
  const int tid = threadIdx.x;
  const int w = tid >> 6, lane = tid & 63;
  const int wr = w >> 1, wc = w & 1;
  // bijective XCD chunk swizzle (nwg divisible by 8)
  const int nbx = gridDim.x;
  const int nwg = nbx * gridDim.y;
  const int orig = blockIdx.x + nbx * blockIdx.y;
  const int tile = (orig & 7) * (nwg >> 3) + (orig >> 3);
  const int bx = tile % nbx, by = tile / nbx;
  const int m0 = by * 128, n0 = bx * 128;
  const int l15 = lane & 15, lhi = lane >> 4;
  const int rowA = lane >> 3;
  const int sgc = (((lane & 7) ^ ((lane >> 3) & 7)) << 3);

  f32x4 acc[4][4] = {};

  const int nk = K >> 6;
  for (int kt = 0; kt < nk; ++kt) {
    const size_t k0 = (size_t)kt << 6;
    if (kt) bar();  // prior compute done reading LDS
#pragma unroll
    for (int it = 0; it < 4; ++it) {
      const int rbase = (w * 4 + it) * 8;  // 8 rows per wave-call
      GLOAD_LDS16(A + (size_t)(m0 + rbase + rowA) * K + k0 + sgc, &As[rbase * 64]);
      GLOAD_LDS16(Bt + (size_t)(n0 + rbase + rowA) * K + k0 + sgc, &Bs[rbase * 64]);
    }
    VMCNT(0);
    bar();  // all waves' staging landed
#pragma unroll
    for (int kk = 0; kk < 2; ++kk) {
      const int gof = (((kk * 4 + lhi) ^ (l15 & 7)) << 3);
      ushort8 a[4], b[4];
#pragma unroll
      for (int i = 0; i < 4; ++i)
        a[i] = *(const ushort8*)&As[(wr * 64 + i * 16 + l15) * 64 + gof];
#pragma unroll
      for (int j = 0; j < 4; ++j)
        b[j] = *(const ushort8*)&Bs[(wc * 64 + j * 16 + l15) * 64 + gof];
#pragma unroll
      for (int i = 0; i < 4; ++i)
#pragma unroll
        for (int j = 0; j < 4; ++j) acc[i][j] = mfma16(a[i], b[j], acc[i][j]);
    }
  }

  const float QSCALE = 0.18033688011112042f;  // 0.125 * log2(e)
#pragma unroll
  for (int i = 0; i < 4; ++i) {
#pragma unroll
    for (int j = 0; j < 4; ++j) {
      const int nn = n0 + wc * 64 + j * 16 + l15;
      const float bv = bias[nn];
#pragma unroll
      for (int r = 0; r < 4; ++r) {
        const int mm = m0 + wr * 64 + i * 16 + lhi * 4 + r;
        const float v = acc[i][j][r] + bv;
        if (mode == 0) {
          outF[(size_t)mm * N + nn] = v;
        } else {
          const int bb = mm >> 11, t = mm & 2047;
          const int c = nn & 1023, h = c >> 6, d = c & 63;
          const size_t idx = ((size_t)(bb * 16 + h) * 2048 + t) * 64 + d;
          const int sec = nn >> 10;
          if (sec == 0) {
            Qb[idx] = f2bf(v * QSCALE);
          } else if (sec == 1) {
            outK[idx] = v; Kb[idx] = f2bf(v);
          } else {
            outV[idx] = v; Vb[idx] = f2bf(v);
          }
        }
      }
    }
  }
}

// ---------------- flash attention ----------------
// Grid 1024 (one q-tile each), XCD-pinned (id%8 == bh%8), long-tiles-first.
// K fragments now load DIRECTLY global->VGPR (L2-resident via XCD pinning),
// double-buffered kfA/kfB with the K-loop unrolled x2 (static reg indexing).
// LDS holds only V^T (dbuf, swizzled) + P (wave-private) = 27 KB.
// S^T = mfma(K,Q) in exp2 domain; defer-max; cvt_pk P-pack; tree reductions.
// All loop-invariant LDS/global offsets hoisted.

__global__ __launch_bounds__(256) void attn_kernel(
    const ushort_t* __restrict__ Qb, const ushort_t* __restrict__ Kb,
    const ushort_t* __restrict__ Vb, ushort_t* __restrict__ Yb) {
  __shared__ __align__(16) ushort_t Vt[2][64 * 72];   // V^T [d][t], swizzled
  __shared__ __align__(16) ushort_t Pl[4 * 16 * 72];  // per-wave P^T' [q][t]
  const int id = blockIdx.x;
  const int xcd = id & 7, win = id >> 3;
  const int qt = 31 - (win >> 2);     // longest blocks first
  const int bh = xcd + 8 * (win & 3);
  const int b = bh >> 4, h = bh & 15;
  const int tid = threadIdx.x, w = tid >> 6, lane = tid & 63;
  const int l15 = lane & 15, lhi = lane >> 4;
  const int swzP = 2 * (l15 & 3);
  const size_t base = (size_t)bh * 2048 * 64;
  const float NEG_INF = -__builtin_inff();
  ushort_t* myP = &Pl[w * 16 * 72];
  const int nkt = qt + 1;

  // ---- hoisted invariant offsets ----
  // K fragment global offsets (elements): row j*16+l15, col kk*32+lhi*8
  int kgo[8];
#pragma unroll
  for (int kk = 0; kk < 2; ++kk)
#pragma unroll
    for (int j = 0; j < 4; ++j)
      kgo[kk * 4 + j] = (j * 16 + l15) * 64 + kk * 32 + lhi * 8;
  // V staging: global offsets (2 per thread: rows t0,t0+1 x 4 d's)
  const int vd0 = (tid & 15) * 4;
  const int vt0b = (tid >> 4) * 2;
  const int vgo0 = vt0b * 64 + vd0;
  const int vgo1 = (vt0b + 32) * 64 + vd0;
  // V^T LDS write offsets (ushort units)
  int lvo[2][4];
#pragma unroll
  for (int it = 0; it < 2; ++it) {
    const int t0 = vt0b + it * 32;
#pragma unroll
    for (int i = 0; i < 4; ++i) {
      const int d = vd0 + i;
      const int scg = (t0 >> 3) ^ ((d >> 3) & 7);
      lvo[it][i] = d * 72 + scg * 8 + (t0 & 7);
    }
  }
  // P write/read offsets
  int pwo[4], pro[2];
#pragma unroll
  for (int j = 0; j < 4; ++j)
    pwo[j] = l15 * 72 + (((j * 2 + (lhi >> 1)) ^ swzP) << 3) + ((lhi & 1) << 2);
#pragma unroll
  for (int kk = 0; kk < 2; ++kk)
    pro[kk] = l15 * 72 + (((kk * 4 + lhi) ^ swzP) << 3);
  // Vt read offsets
  int vro[8];
#pragma unroll
  for (int kk = 0; kk < 2; ++kk)
#pragma unroll
    for (int df = 0; df < 4; ++df) {
      const int r = df * 16 + l15;
      vro[kk * 4 + df] = r * 72 + (((kk * 4 + lhi) ^ ((r >> 3) & 7)) << 3);
    }

  // Q fragments (B-operand)
  ushort8 qf[2];
  {
    const size_t qrow = base + (size_t)(qt * 64 + w * 16 + l15) * 64;
    qf[0] = *(const ushort8*)&Qb[qrow + lhi * 8];
    qf[1] = *(const ushort8*)&Qb[qrow + 32 + lhi * 8];
  }
  float m_s = NEG_INF, l_s = 0.f;
  f32x4 o[4] = {};
  ushort8 kfA[8], kfB[8];

  // prologue: K frags tile 0 -> kfA; V tile 0 -> regs -> Vt[0]
  {
#pragma unroll
    for (int i = 0; i < 8; ++i)
      kfA[i] = *(const ushort8*)&Kb[base + kgo[i]];
    const ushort_t* vp0 = Vb + base + vgo0;
    const ushort_t* vp1 = Vb + base + vgo1;
    u64_t a0 = *(const u64_t*)vp0, c0 = *(const u64_t*)(vp0 + 64);
    u64_t a1 = *(const u64_t*)vp1, c1 = *(const u64_t*)(vp1 + 64);
    us4 av0 = __builtin_bit_cast(us4, a0), cv0 = __builtin_bit_cast(us4, c0);
    us4 av1 = __builtin_bit_cast(us4, a1), cv1 = __builtin_bit_cast(us4, c1);
#pragma unroll
    for (int i = 0; i < 4; ++i) {
      *(unsigned int*)&Vt[0][lvo[0][i]] =
          (unsigned int)av0[i] | ((unsigned int)cv0[i] << 16);
      *(unsigned int*)&Vt[0][lvo[1][i]] =
          (unsigned int)av1[i] | ((unsigned int)cv1[i] << 16);
    }
  }
  __syncthreads();

  const int qloc = w * 16 + l15;

  auto step = [&](int kt, ushort8 (&kfu)[8], ushort8 (&kfl)[8],
                  const int cur) __attribute__((always_inline)) {
    const int nxt = cur ^ 1;
    const bool pf = (kt + 1 < nkt);
    const size_t tb = base + (size_t)(kt + 1) * 4096;
    // issue next-tile V loads (global->reg) first: full step to land
    u64_t va0 = 0, vc0 = 0, va1 = 0, vc1 = 0;
    if (pf) {
      const ushort_t* vp0 = Vb + tb + vgo0;
      const ushort_t* vp1 = Vb + tb + vgo1;
      va0 = *(const u64_t*)vp0; vc0 = *(const u64_t*)(vp0 + 64);
      va1 = *(const u64_t*)vp1; vc1 = *(const u64_t*)(vp1 + 64);
      // issue next-tile K loads into the other buffer
#pragma unroll
      for (int i = 0; i < 8; ++i)
        kfl[i] = *(const ushort8*)&Kb[tb + kgo[i]];
    }

    // S^T = mfma(K, Q)
    f32x4 s[4] = {};
#pragma unroll
    for (int kk = 0; kk < 2; ++kk)
#pragma unroll
      for (int j = 0; j < 4; ++j)
        s[j] = mfma16(kfu[kk * 4 + j], qf[kk], s[j]);

    // causal mask (diagonal tile only); S already in exp2 domain
    if (kt == qt) {
#pragma unroll
      for (int j = 0; j < 4; ++j)
#pragma unroll
        for (int r = 0; r < 4; ++r)
          if ((j * 16 + lhi * 4 + r) > qloc) s[j][r] = NEG_INF;
    }

    // tree max
    float mj[4];
#pragma unroll
    for (int j = 0; j < 4; ++j)
      mj[j] = fmaxf(fmaxf(s[j][0], s[j][1]), fmaxf(s[j][2], s[j][3]));
    float pmax = fmaxf(fmaxf(mj[0], mj[1]), fmaxf(mj[2], mj[3]));
    pmax = fmaxf(pmax, __shfl_xor(pmax, 16));
    pmax = fmaxf(pmax, __shfl_xor(pmax, 32));
    // defer-max: only rescale when the running max grew by > 8
    if (__any(pmax - m_s > 8.0f)) {
      const float mnew = fmaxf(m_s, pmax);
      const float al = exp2v(m_s - mnew);
      m_s = mnew;
      l_s *= al;
#pragma unroll
      for (int df = 0; df < 4; ++df)
#pragma unroll
        for (int r = 0; r < 4; ++r) o[df][r] *= al;
    }
    // exp + tree sum
#pragma unroll
    for (int j = 0; j < 4; ++j)
#pragma unroll
      for (int r = 0; r < 4; ++r) s[j][r] = exp2v(s[j][r] - m_s);
    float rj[4];
#pragma unroll
    for (int j = 0; j < 4; ++j)
      rj[j] = (s[j][0] + s[j][1]) + (s[j][2] + s[j][3]);
    float rsum = (rj[0] + rj[1]) + (rj[2] + rj[3]);
    rsum += __shfl_xor(rsum, 16);
    rsum += __shfl_xor(rsum, 32);
    l_s += rsum;

    // P^T pack -> LDS (wave-private, swizzled b64 writes)
#pragma unroll
    for (int j = 0; j < 4; ++j) {
      const unsigned int w0 = cvtpk(s[j][0], s[j][1]);
      const unsigned int w1 = cvtpk(s[j][2], s[j][3]);
      *(u64_t*)&myP[pwo[j]] = (u64_t)w0 | ((u64_t)w1 << 32);
    }

    // O^T += mfma(V^T-frag, P^T-frag)
#pragma unroll
    for (int kk = 0; kk < 2; ++kk) {
      ushort8 pa = *(const ushort8*)&myP[pro[kk]];
#pragma unroll
      for (int df = 0; df < 4; ++df) {
        ushort8 vb = *(const ushort8*)&Vt[cur][vro[kk * 4 + df]];
        o[df] = mfma16(vb, pa, o[df]);
      }
    }

    // write-late: V^T for next tile
    if (pf) {
      us4 av0 = __builtin_bit_cast(us4, va0), cv0 = __builtin_bit_cast(us4, vc0);
      us4 av1 = __builtin_bit_cast(us4, va1), cv1 = __builtin_bit_cast(us4, vc1);
#pragma unroll
      for (int i = 0; i < 4; ++i) {
        *(unsigned int*)&Vt[nxt][lvo[0][i]] =
            (unsigned int)av0[i] | ((unsigned int)cv0[i] << 16);
        *(unsigned int*)&Vt[nxt][lvo[1][i]] =
            (unsigned int)av1[i] | ((unsigned int)cv1[i] << 16);
      }
    }
    __syncthreads();
  };

  int kt = 0;
  for (;;) {
    step(kt, kfA, kfB, 0);
    if (++kt == nkt) break;
    step(kt, kfB, kfA, 1);
    if (++kt == nkt) break;
  }

  // epilogue: lane holds O^T[d = df*16+lhi*4+r][q = w*16+l15]
  const float inv = 1.0f / l_s;
  const size_t yrow = (size_t)(b * 2048 + qt * 64 + w * 16 + l15) * 1024 + h * 64;
#pragma unroll
  for (int df = 0; df < 4; ++df) {
    us4 ov;
#pragma unroll
    for (int r = 0; r < 4; ++r) ov[r] = f2bf(o[df][r] * inv);
    *(us4*)&Yb[yrow + df * 16 + lhi * 4] = ov;
  }
}

// ---------------- launch ----------------

extern "C" void kernel_launch(void* const* d_in, const int* in_sizes, int n_in,
                              void* d_out, int out_size, void* d_ws, size_t ws_size,
                              hipStream_t stream) {
  const float* x      = (const float*)d_in[0];
  const float* W_kqv  = (const float*)d_in[1];
  const float* b_kqv  = (const float*)d_in[2];
  const float* W_proj = (const float*)d_in[3];
  const float* b_proj = (const float*)d_in[4];
  float* out  = (float*)d_out;          // [B,T,C] fp32
  float* outK = out + 4194304;          // [B,H,T,D] fp32
  float* outV = out + 8388608;          // [B,H,T,D] fp32

  char* ws = (char*)d_ws;
  ushort_t* Xb  = (ushort_t*)(ws);
  ushort_t* Wkt = (ushort_t*)(ws + ((size_t)8 << 20));
  ushort_t* Wpt = (ushort_t*)(ws + ((size_t)14 << 20));
  ushort_t* Qb  = (ushort_t*)(ws + ((size_t)16 << 20));
  ushort_t* Kb  = (ushort_t*)(ws + ((size_t)24 << 20));
  ushort_t* Vb  = (ushort_t*)(ws + ((size_t)32 << 20));
  ushort_t* Yb  = Xb;  // Xb dead after QKV GEMM

  cast_x_kernel<<<2048, 256, 0, stream>>>(x, Xb, 524288);
  transpose_cast_kernel<<<dim3(96, 32), 256, 0, stream>>>(W_kqv, Wkt, 1024, 3072);
  transpose_cast_kernel<<<dim3(32, 32), 256, 0, stream>>>(W_proj, Wpt, 1024, 1024);
  gemm_bt_kernel<<<dim3(24, 32), 256, 0, stream>>>(
      Xb, Wkt, b_kqv, nullptr, outK, outV, Qb, Kb, Vb, 4096, 3072, 1024, 1);
  attn_kernel<<<1024, 256, 0, stream>>>(Qb, Kb, Vb, Yb);
  gemm_bt_kernel<<<dim3(8, 32), 256, 0, stream>>>(
      Yb, Wpt, b_proj, out, nullptr, nullptr, nullptr, nullptr, nullptr,
      4096, 1024, 1024, 0);
}

// Round 10
// 120.118 us; speedup vs baseline: 1.2317x; 1.2317x over previous
//
#include <hip/hip_runtime.h>

// Workspace layout (40 MB total):
//   [0,  8M)  Xb  bf16 [4096][1024]   (reused as Yb after QKV GEMM)
//   [8, 14M)  Wkqv_t bf16 [3072][1024]
//   [14,16M)  Wproj_t bf16 [1024][1024]
//   [16,24M)  Qb bf16 [B,H,T,D]  (pre-scaled by 0.125*log2e)
//   [24,32M)  Kb bf16 [B,H,T,D]
//   [32,40M)  Vb bf16 [B,H,T,D]

#define DEVI __device__ __forceinline__

typedef unsigned short ushort_t;
typedef unsigned long long u64_t;
typedef __attribute__((ext_vector_type(4))) unsigned short us4;
typedef __attribute__((ext_vector_type(8))) unsigned short ushort8;
typedef __attribute__((ext_vector_type(4))) float f32x4;
typedef __attribute__((ext_vector_type(8))) __bf16 bf16x8;

DEVI unsigned short f2bf(float f) {
  union { float f; unsigned int u; } c; c.f = f;
  unsigned int u = c.u;
  unsigned int r = (u + 0x7FFFu + ((u >> 16) & 1u)) >> 16;
  return (unsigned short)r;
}

// exp2 via raw v_exp_f32 (1 VALU trans op; s_nop covers the RAW hazard)
DEVI float exp2v(float x) {
  float r;
  asm("v_exp_f32 %0, %1\n\ts_nop 0" : "=v"(r) : "v"(x));
  return r;
}

// pack 2 fp32 -> 2 bf16 (RNE) in one instruction
DEVI unsigned int cvtpk(float lo, float hi) {
  unsigned int r;
  asm("v_cvt_pk_bf16_f32 %0, %1, %2" : "=v"(r) : "v"(lo), "v"(hi));
  return r;
}

DEVI f32x4 mfma16(ushort8 a, ushort8 b, f32x4 c) {
  return __builtin_amdgcn_mfma_f32_16x16x32_bf16(
      __builtin_bit_cast(bf16x8, a), __builtin_bit_cast(bf16x8, b), c, 0, 0, 0);
}

typedef const __attribute__((address_space(1))) void* gptr_t;
typedef __attribute__((address_space(3))) void* lptr_t;
#define GLOAD_LDS16(g, l) \
  __builtin_amdgcn_global_load_lds((gptr_t)(g), (lptr_t)(l), 16, 0, 0)

DEVI void bar() {
  asm volatile("" ::: "memory");
  __builtin_amdgcn_s_barrier();
  asm volatile("" ::: "memory");
}
#define VMCNT(n) asm volatile("s_waitcnt vmcnt(" #n ")" ::: "memory")

// ---------------- prep kernels ----------------

__global__ void cast_x_kernel(const float* __restrict__ in,
                              ushort_t* __restrict__ out, int n8) {
  int i = blockIdx.x * blockDim.x + threadIdx.x;
  if (i >= n8) return;
  const f32x4* p = (const f32x4*)in;
  f32x4 a = p[2 * i], b = p[2 * i + 1];
  ushort8 o;
  o[0] = f2bf(a[0]); o[1] = f2bf(a[1]); o[2] = f2bf(a[2]); o[3] = f2bf(a[3]);
  o[4] = f2bf(b[0]); o[5] = f2bf(b[1]); o[6] = f2bf(b[2]); o[7] = f2bf(b[3]);
  ((ushort8*)out)[i] = o;
}

// out[c][r] = bf16(in[r][c]); in is [R][Cin], out is [Cin][R]
__global__ void transpose_cast_kernel(const float* __restrict__ in,
                                      ushort_t* __restrict__ out, int R, int Cin) {
  __shared__ float tile[32][33];
  int c0 = blockIdx.x * 32, r0 = blockIdx.y * 32;
  int tx = threadIdx.x & 31, ty = threadIdx.x >> 5;
#pragma unroll
  for (int it = 0; it < 4; ++it)
    tile[ty + it * 8][tx] = in[(size_t)(r0 + ty + it * 8) * Cin + c0 + tx];
  __syncthreads();
#pragma unroll
  for (int it = 0; it < 4; ++it)
    out[(size_t)(c0 + ty + it * 8) * R + r0 + tx] = f2bf(tile[tx][ty + it * 8]);
}

// ---------------- GEMM: C = A[M,K] * Bt[N,K]^T + bias ----------------
// mode 0: write fp32 out[M][N]
// mode 1: QKV epilogue (scatter q/k/v; Qb pre-scaled by 0.125*log2e for attn)
// m97 structure: 128x128 tile, BK=64, SINGLE-buffered LDS (32 KB), 2
// barriers/kt, conflict-free XOR swizzle, XCD swizzle.

__global__ __launch_bounds__(256) void gemm_bt_kernel(
    const ushort_t* __restrict__ A, const ushort_t* __restrict__ Bt,
    const float* __restrict__ bias, float* __restrict__ outF,
    float* __restrict__ outK, float* __restrict__ outV,
    ushort_t* __restrict__ Qb, ushort_t* __restrict__ Kb, ushort_t* __restrict__ Vb,
    int M, int N, int K, int mode) {
  __shared__ __align__(16) ushort_t As[128 * 64];
  __shared__ __align__(16) ushort_t Bs[128 * 64];
  const int tid = threadIdx.x;
  const int w = tid >> 6, lane = tid & 63;
  const int wr = w >> 1, wc = w & 1;
  // bijective XCD chunk swizzle (nwg divisible by 8)
  const int nbx = gridDim.x;
  const int nwg = nbx * gridDim.y;
  const int orig = blockIdx.x + nbx * blockIdx.y;
  const int tile = (orig & 7) * (nwg >> 3) + (orig >> 3);
  const int bx = tile % nbx, by = tile / nbx;
  const int m0 = by * 128, n0 = bx * 128;
  const int l15 = lane & 15, lhi = lane >> 4;
  const int rowA = lane >> 3;
  const int sgc = (((lane & 7) ^ ((lane >> 3) & 7)) << 3);

  f32x4 acc[4][4] = {};

  const int nk = K >> 6;
  for (int kt = 0; kt < nk; ++kt) {
    const size_t k0 = (size_t)kt << 6;
    if (kt) bar();  // prior compute done reading LDS
#pragma unroll
    for (int it = 0; it < 4; ++it) {
      const int rbase = (w * 4 + it) * 8;  // 8 rows per wave-call
      GLOAD_LDS16(A + (size_t)(m0 + rbase + rowA) * K + k0 + sgc, &As[rbase * 64]);
      GLOAD_LDS16(Bt + (size_t)(n0 + rbase + rowA) * K + k0 + sgc, &Bs[rbase * 64]);
    }
    VMCNT(0);
    bar();  // all waves' staging landed
#pragma unroll
    for (int kk = 0; kk < 2; ++kk) {
      const int gof = (((kk * 4 + lhi) ^ (l15 & 7)) << 3);
      ushort8 a[4], b[4];
#pragma unroll
      for (int i = 0; i < 4; ++i)
        a[i] = *(const ushort8*)&As[(wr * 64 + i * 16 + l15) * 64 + gof];
#pragma unroll
      for (int j = 0; j < 4; ++j)
        b[j] = *(const ushort8*)&Bs[(wc * 64 + j * 16 + l15) * 64 + gof];
#pragma unroll
      for (int i = 0; i < 4; ++i)
#pragma unroll
        for (int j = 0; j < 4; ++j) acc[i][j] = mfma16(a[i], b[j], acc[i][j]);
    }
  }

  const float QSCALE = 0.18033688011112042f;  // 0.125 * log2(e)
#pragma unroll
  for (int i = 0; i < 4; ++i) {
#pragma unroll
    for (int j = 0; j < 4; ++j) {
      const int nn = n0 + wc * 64 + j * 16 + l15;
      const float bv = bias[nn];
#pragma unroll
      for (int r = 0; r < 4; ++r) {
        const int mm = m0 + wr * 64 + i * 16 + lhi * 4 + r;
        const float v = acc[i][j][r] + bv;
        if (mode == 0) {
          outF[(size_t)mm * N + nn] = v;
        } else {
          const int bb = mm >> 11, t = mm & 2047;
          const int c = nn & 1023, h = c >> 6, d = c & 63;
          const size_t idx = ((size_t)(bb * 16 + h) * 2048 + t) * 64 + d;
          const int sec = nn >> 10;
          if (sec == 0) {
            Qb[idx] = f2bf(v * QSCALE);
          } else if (sec == 1) {
            outK[idx] = v; Kb[idx] = f2bf(v);
          } else {
            outV[idx] = v; Vb[idx] = f2bf(v);
          }
        }
      }
    }
  }
}

// ---------------- flash attention (round-8 structure + T5 setprio) ----------------
// Grid 1024 (one q-tile each), XCD-pinned (id%8 == bh%8), long-tiles-first.
// S^T = mfma(K,Q) in exp2 domain (Q pre-scaled by 0.125*log2e).
// Defer-max (THR=8); cvt_pk P-pack; K via swizzled global_load_lds (dbuf);
// V^T reg-staged (issue-early/write-late); s_setprio around MFMA clusters.

__global__ __launch_bounds__(256) void attn_kernel(
    const ushort_t* __restrict__ Qb, const ushort_t* __restrict__ Kb,
    const ushort_t* __restrict__ Vb, ushort_t* __restrict__ Yb) {
  __shared__ __align__(16) ushort_t Ks[2][64 * 64];   // K [t][d], chunk-swizzled
  __shared__ __align__(16) ushort_t Vt[2][64 * 72];   // V^T [d][t], swizzled
  __shared__ __align__(16) ushort_t Pl[4 * 16 * 72];  // per-wave P^T' [q][t], swizzled
  const int id = blockIdx.x;
  const int xcd = id & 7, win = id >> 3;
  const int qt = 31 - (win >> 2);     // longest blocks first
  const int bh = xcd + 8 * (win & 3);
  const int b = bh >> 4, h = bh & 15;
  const int tid = threadIdx.x, w = tid >> 6, lane = tid & 63;
  const int l15 = lane & 15, lhi = lane >> 4;
  const int swzP = 2 * (l15 & 3);
  const size_t base = (size_t)bh * 2048 * 64;
  const float NEG_INF = -__builtin_inff();
  ushort_t* myP = &Pl[w * 16 * 72];

  // V-staging thread geometry (per it: t0 = even row, 4 d's)
  const int vd0 = (tid & 15) * 4;
  const int vt0b = (tid >> 4) * 2;

  const int nkt = qt + 1;

  // Q fragments (B-operand): lane holds Q[q = w*16+l15][d = kk*32+lhi*8 ..]
  ushort8 qf[2];
  {
    const size_t qrow = base + (size_t)(qt * 64 + w * 16 + l15) * 64;
    qf[0] = *(const ushort8*)&Qb[qrow + lhi * 8];
    qf[1] = *(const ushort8*)&Qb[qrow + 32 + lhi * 8];
  }
  float m_s = NEG_INF, l_s = 0.f;
  f32x4 o[4] = {};

  // prologue: stage tile 0 into buf 0
  {
#pragma unroll
    for (int it = 0; it < 2; ++it) {
      const int chunk = tid + it * 256;
      const int row = chunk >> 3, g = chunk & 7;
      const int sg = g ^ (row & 7);
      GLOAD_LDS16(Kb + base + (size_t)row * 64 + sg * 8, &Ks[0][chunk * 8]);
    }
#pragma unroll
    for (int it = 0; it < 2; ++it) {
      const int t0 = vt0b + it * 32;
      const ushort_t* vp = Vb + base + (size_t)t0 * 64 + vd0;
      u64_t a = *(const u64_t*)vp;
      u64_t c = *(const u64_t*)(vp + 64);
      us4 av = __builtin_bit_cast(us4, a);
      us4 cv = __builtin_bit_cast(us4, c);
#pragma unroll
      for (int i = 0; i < 4; ++i) {
        const int d = vd0 + i;
        const int scg = (t0 >> 3) ^ ((d >> 3) & 7);
        unsigned int wv = (unsigned int)av[i] | ((unsigned int)cv[i] << 16);
        *(unsigned int*)&Vt[0][d * 72 + scg * 8 + (t0 & 7)] = wv;
      }
    }
  }
  __syncthreads();

  for (int kt = 0; kt < nkt; ++kt) {
    const int cur = kt & 1, nxt = cur ^ 1;
    const bool pf = (kt + 1 < nkt);
    u64_t va[2], vc[2];
    if (pf) {
      const size_t tb = base + (size_t)(kt + 1) * 64 * 64;
#pragma unroll
      for (int it = 0; it < 2; ++it) {
        const int chunk = tid + it * 256;
        const int row = chunk >> 3, g = chunk & 7;
        const int sg = g ^ (row & 7);
        GLOAD_LDS16(Kb + tb + (size_t)row * 64 + sg * 8, &Ks[nxt][chunk * 8]);
      }
#pragma unroll
      for (int it = 0; it < 2; ++it) {
        const int t0 = vt0b + it * 32;
        const ushort_t* vp = Vb + tb + (size_t)t0 * 64 + vd0;
        va[it] = *(const u64_t*)vp;
        vc[it] = *(const u64_t*)(vp + 64);
      }
    }

    // S^T = mfma(K, Q): s[j] rows t = j*16+lhi*4+r, col q = w*16+l15
    f32x4 s[4] = {};
    __builtin_amdgcn_s_setprio(1);
#pragma unroll
    for (int kk = 0; kk < 2; ++kk) {
#pragma unroll
      for (int j = 0; j < 4; ++j) {
        const int g = (kk * 4 + lhi) ^ (l15 & 7);
        ushort8 kb = *(const ushort8*)&Ks[cur][(j * 16 + l15) * 64 + g * 8];
        s[j] = mfma16(kb, qf[kk], s[j]);
      }
    }
    __builtin_amdgcn_s_setprio(0);
    // causal mask (diagonal tile only); S already in exp2 domain
    const int qloc = w * 16 + l15;
    if (kt == qt) {
#pragma unroll
      for (int j = 0; j < 4; ++j)
#pragma unroll
        for (int r = 0; r < 4; ++r)
          if ((j * 16 + lhi * 4 + r) > qloc) s[j][r] = NEG_INF;
    }

    // in-lane softmax for q-row l15 (partials across lhi group)
    float pmax = s[0][0];
#pragma unroll
    for (int j = 0; j < 4; ++j)
#pragma unroll
      for (int r = 0; r < 4; ++r) pmax = fmaxf(pmax, s[j][r]);
    pmax = fmaxf(pmax, __shfl_xor(pmax, 16));
    pmax = fmaxf(pmax, __shfl_xor(pmax, 32));
    // defer-max: only rescale when the running max grew by > 8 (P <= 2^8)
    if (__any(pmax - m_s > 8.0f)) {
      const float mnew = fmaxf(m_s, pmax);
      const float al = exp2v(m_s - mnew);
      m_s = mnew;
      l_s *= al;
#pragma unroll
      for (int df = 0; df < 4; ++df)
#pragma unroll
        for (int r = 0; r < 4; ++r) o[df][r] *= al;
    }
    float rsum = 0.f;
#pragma unroll
    for (int j = 0; j < 4; ++j)
#pragma unroll
      for (int r = 0; r < 4; ++r) {
        const float pe = exp2v(s[j][r] - m_s);
        s[j][r] = pe;
        rsum += pe;
      }
    rsum += __shfl_xor(rsum, 16);
    rsum += __shfl_xor(rsum, 32);
    l_s += rsum;

    // P^T pack -> LDS (wave-private, swizzled b64 writes, cvt_pk)
#pragma unroll
    for (int j = 0; j < 4; ++j) {
      const unsigned int w0 = cvtpk(s[j][0], s[j][1]);
      const unsigned int w1 = cvtpk(s[j][2], s[j][3]);
      const u64_t dw = (u64_t)w0 | ((u64_t)w1 << 32);
      const int cg = j * 2 + (lhi >> 1);
      *(u64_t*)&myP[l15 * 72 + ((cg ^ swzP) << 3) + ((lhi & 1) << 2)] = dw;
    }

    // O^T += mfma(V^T-frag, P^T-frag)
    __builtin_amdgcn_s_setprio(1);
#pragma unroll
    for (int kk = 0; kk < 2; ++kk) {
      ushort8 pa = *(const ushort8*)&myP[l15 * 72 + (((kk * 4 + lhi) ^ swzP) << 3)];
#pragma unroll
      for (int df = 0; df < 4; ++df) {
        const int r = df * 16 + l15;
        const int g = (kk * 4 + lhi) ^ ((r >> 3) & 7);
        ushort8 vb = *(const ushort8*)&Vt[cur][r * 72 + g * 8];
        o[df] = mfma16(vb, pa, o[df]);
      }
    }
    __builtin_amdgcn_s_setprio(0);

    // write-late: V^T for next tile
    if (pf) {
#pragma unroll
      for (int it = 0; it < 2; ++it) {
        const int t0 = vt0b + it * 32;
        us4 av = __builtin_bit_cast(us4, va[it]);
        us4 cv = __builtin_bit_cast(us4, vc[it]);
#pragma unroll
        for (int i = 0; i < 4; ++i) {
          const int d = vd0 + i;
          const int scg = (t0 >> 3) ^ ((d >> 3) & 7);
          unsigned int wv = (unsigned int)av[i] | ((unsigned int)cv[i] << 16);
          *(unsigned int*)&Vt[nxt][d * 72 + scg * 8 + (t0 & 7)] = wv;
        }
      }
    }
    __syncthreads();
  }

  // epilogue: lane holds O^T[d = df*16+lhi*4+r][q = w*16+l15]
  const float inv = 1.0f / l_s;
  const size_t yrow = (size_t)(b * 2048 + qt * 64 + w * 16 + l15) * 1024 + h * 64;
#pragma unroll
  for (int df = 0; df < 4; ++df) {
    us4 ov;
#pragma unroll
    for (int r = 0; r < 4; ++r) ov[r] = f2bf(o[df][r] * inv);
    *(us4*)&Yb[yrow + df * 16 + lhi * 4] = ov;
  }
}

// ---------------- launch ----------------

extern "C" void kernel_launch(void* const* d_in, const int* in_sizes, int n_in,
                              void* d_out, int out_size, void* d_ws, size_t ws_size,
                              hipStream_t stream) {
  const float* x      = (const float*)d_in[0];
  const float* W_kqv  = (const float*)d_in[1];
  const float* b_kqv  = (const float*)d_in[2];
  const float* W_proj = (const float*)d_in[3];
  const float* b_proj = (const float*)d_in[4];
  float* out  = (float*)d_out;          // [B,T,C] fp32
  float* outK = out + 4194304;          // [B,H,T,D] fp32
  float* outV = out + 8388608;          // [B,H,T,D] fp32

  char* ws = (char*)d_ws;
  ushort_t* Xb  = (ushort_t*)(ws);
  ushort_t* Wkt = (ushort_t*)(ws + ((size_t)8 << 20));
  ushort_t* Wpt = (ushort_t*)(ws + ((size_t)14 << 20));
  ushort_t* Qb  = (ushort_t*)(ws + ((size_t)16 << 20));
  ushort_t* Kb  = (ushort_t*)(ws + ((size_t)24 << 20));
  ushort_t* Vb  = (ushort_t*)(ws + ((size_t)32 << 20));
  ushort_t* Yb  = Xb;  // Xb dead after QKV GEMM

  cast_x_kernel<<<2048, 256, 0, stream>>>(x, Xb, 524288);
  transpose_cast_kernel<<<dim3(96, 32), 256, 0, stream>>>(W_kqv, Wkt, 1024, 3072);
  transpose_cast_kernel<<<dim3(32, 32), 256, 0, stream>>>(W_proj, Wpt, 1024, 1024);
  gemm_bt_kernel<<<dim3(24, 32), 256, 0, stream>>>(
      Xb, Wkt, b_kqv, nullptr, outK, outV, Qb, Kb, Vb, 4096, 3072, 1024, 1);
  attn_kernel<<<1024, 256, 0, stream>>>(Qb, Kb, Vb, Yb);
  gemm_bt_kernel<<<dim3(8, 32), 256, 0, stream>>>(
      Yb, Wpt, b_proj, out, nullptr, nullptr, nullptr, nullptr, nullptr,
      4096, 1024, 1024, 0);
}

// Round 13
// 114.510 us; speedup vs baseline: 1.2920x; 1.0490x over previous
//
#include <hip/hip_runtime.h>

// Workspace layout (40 MB total):
//   [0,  8M)  Xb  bf16 [4096][1024]   (reused as Yb after QKV GEMM)
//   [8, 14M)  Wkqv_t bf16 [3072][1024]
//   [14,16M)  Wproj_t bf16 [1024][1024]
//   [16,24M)  Qb bf16 [B,H,T,D]  (pre-scaled by 0.125*log2e)
//   [24,32M)  Kb bf16 [B,H,T,D]
//   [32,40M)  Vb bf16 [B,H,T,D]

#define DEVI __device__ __forceinline__

typedef unsigned short ushort_t;
typedef unsigned long long u64_t;
typedef __attribute__((ext_vector_type(4))) unsigned short us4;
typedef __attribute__((ext_vector_type(8))) unsigned short ushort8;
typedef __attribute__((ext_vector_type(4))) float f32x4;
typedef __attribute__((ext_vector_type(8))) __bf16 bf16x8;

DEVI unsigned short f2bf(float f) {
  union { float f; unsigned int u; } c; c.f = f;
  unsigned int u = c.u;
  unsigned int r = (u + 0x7FFFu + ((u >> 16) & 1u)) >> 16;
  return (unsigned short)r;
}

// exp2 via raw v_exp_f32 (1 VALU trans op; s_nop covers the RAW hazard)
DEVI float exp2v(float x) {
  float r;
  asm("v_exp_f32 %0, %1\n\ts_nop 0" : "=v"(r) : "v"(x));
  return r;
}

// pack 2 fp32 -> 2 bf16 (RNE) in one instruction
DEVI unsigned int cvtpk(float lo, float hi) {
  unsigned int r;
  asm("v_cvt_pk_bf16_f32 %0, %1, %2" : "=v"(r) : "v"(lo), "v"(hi));
  return r;
}

DEVI f32x4 mfma16(ushort8 a, ushort8 b, f32x4 c) {
  return __builtin_amdgcn_mfma_f32_16x16x32_bf16(
      __builtin_bit_cast(bf16x8, a), __builtin_bit_cast(bf16x8, b), c, 0, 0, 0);
}

typedef const __attribute__((address_space(1))) void* gptr_t;
typedef __attribute__((address_space(3))) void* lptr_t;
#define GLOAD_LDS16(g, l) \
  __builtin_amdgcn_global_load_lds((gptr_t)(g), (lptr_t)(l), 16, 0, 0)

DEVI void bar() {
  asm volatile("" ::: "memory");
  __builtin_amdgcn_s_barrier();
  asm volatile("" ::: "memory");
}
#define VMCNT(n) asm volatile("s_waitcnt vmcnt(" #n ")" ::: "memory")

// ---------------- fused prep kernel ----------------
// blocks [0,2048): cast x -> Xb (bf16)
// blocks [2048,5120): transpose+cast W_kqv -> Wkt [3072][1024]
// blocks [5120,6144): transpose+cast W_proj -> Wpt [1024][1024]

__global__ void prep_kernel(const float* __restrict__ x,
                            const float* __restrict__ Wk,
                            const float* __restrict__ Wp,
                            ushort_t* __restrict__ Xb,
                            ushort_t* __restrict__ Wkt,
                            ushort_t* __restrict__ Wpt) {
  __shared__ float tile[32][33];
  const int id = blockIdx.x, tid = threadIdx.x;
  if (id < 2048) {
    const int i = id * 256 + tid;
    const f32x4* p = (const f32x4*)x;
    f32x4 a = p[2 * i], b = p[2 * i + 1];
    ushort8 o;
    o[0] = f2bf(a[0]); o[1] = f2bf(a[1]); o[2] = f2bf(a[2]); o[3] = f2bf(a[3]);
    o[4] = f2bf(b[0]); o[5] = f2bf(b[1]); o[6] = f2bf(b[2]); o[7] = f2bf(b[3]);
    ((ushort8*)Xb)[i] = o;
    return;
  }
  const float* in;
  ushort_t* outp;
  int R = 1024, Cin, bx, by;
  if (id < 5120) {
    const int jid = id - 2048;
    bx = jid % 96; by = jid / 96; in = Wk; outp = Wkt; Cin = 3072;
  } else {
    const int jid = id - 5120;
    bx = jid % 32; by = jid / 32; in = Wp; outp = Wpt; Cin = 1024;
  }
  const int c0 = bx * 32, r0 = by * 32;
  const int tx = tid & 31, ty = tid >> 5;
#pragma unroll
  for (int it = 0; it < 4; ++it)
    tile[ty + it * 8][tx] = in[(size_t)(r0 + ty + it * 8) * Cin + c0 + tx];
  __syncthreads();
#pragma unroll
  for (int it = 0; it < 4; ++it)
    outp[(size_t)(c0 + ty + it * 8) * R + r0 + tx] = f2bf(tile[tx][ty + it * 8]);
}

// ---------------- GEMM: C = A[M,K] * Bt[N,K]^T + bias ----------------
// mode 0: write fp32 out[M][N]
// mode 1: QKV epilogue (scatter q/k/v; Qb pre-scaled by 0.125*log2e for attn)
// m97 structure: 128x128 tile, BK=64, SINGLE-buffered LDS (32 KB), 2
// barriers/kt, conflict-free XOR swizzle, XCD swizzle.

__global__ __launch_bounds__(256) void gemm_bt_kernel(
    const ushort_t* __restrict__ A, const ushort_t* __restrict__ Bt,
    const float* __restrict__ bias, float* __restrict__ outF,
    float* __restrict__ outK, float* __restrict__ outV,
    ushort_t* __restrict__ Qb, ushort_t* __restrict__ Kb, ushort_t* __restrict__ Vb,
    int M, int N, int K, int mode) {
  __shared__ __align__(16) ushort_t As[128 * 64];
  __shared__ __align__(16) ushort_t Bs[128 * 64];
  const int tid = threadIdx.x;
  const int w = tid >> 6, lane = tid & 63;
  const int wr = w >> 1, wc = w & 1;
  const int nbx = gridDim.x;
  const int nwg = nbx * gridDim.y;
  const int orig = blockIdx.x + nbx * blockIdx.y;
  const int tile = (orig & 7) * (nwg >> 3) + (orig >> 3);
  const int bx = tile % nbx, by = tile / nbx;
  const int m0 = by * 128, n0 = bx * 128;
  const int l15 = lane & 15, lhi = lane >> 4;
  const int rowA = lane >> 3;
  const int sgc = (((lane & 7) ^ ((lane >> 3) & 7)) << 3);

  f32x4 acc[4][4] = {};

  const int nk = K >> 6;
  for (int kt = 0; kt < nk; ++kt) {
    const size_t k0 = (size_t)kt << 6;
    if (kt) bar();
#pragma unroll
    for (int it = 0; it < 4; ++it) {
      const int rbase = (w * 4 + it) * 8;
      GLOAD_LDS16(A + (size_t)(m0 + rbase + rowA) * K + k0 + sgc, &As[rbase * 64]);
      GLOAD_LDS16(Bt + (size_t)(n0 + rbase + rowA) * K + k0 + sgc, &Bs[rbase * 64]);
    }
    VMCNT(0);
    bar();
#pragma unroll
    for (int kk = 0; kk < 2; ++kk) {
      const int gof = (((kk * 4 + lhi) ^ (l15 & 7)) << 3);
      ushort8 a[4], b[4];
#pragma unroll
      for (int i = 0; i < 4; ++i)
        a[i] = *(const ushort8*)&As[(wr * 64 + i * 16 + l15) * 64 + gof];
#pragma unroll
      for (int j = 0; j < 4; ++j)
        b[j] = *(const ushort8*)&Bs[(wc * 64 + j * 16 + l15) * 64 + gof];
#pragma unroll
      for (int i = 0; i < 4; ++i)
#pragma unroll
        for (int j = 0; j < 4; ++j) acc[i][j] = mfma16(a[i], b[j], acc[i][j]);
    }
  }

  const float QSCALE = 0.18033688011112042f;  // 0.125 * log2(e)
#pragma unroll
  for (int i = 0; i < 4; ++i) {
#pragma unroll
    for (int j = 0; j < 4; ++j) {
      const int nn = n0 + wc * 64 + j * 16 + l15;
      const float bv = bias[nn];
#pragma unroll
      for (int r = 0; r < 4; ++r) {
        const int mm = m0 + wr * 64 + i * 16 + lhi * 4 + r;
        const float v = acc[i][j][r] + bv;
        if (mode == 0) {
          outF[(size_t)mm * N + nn] = v;
        } else {
          const int bb = mm >> 11, t = mm & 2047;
          const int c = nn & 1023, h = c >> 6, d = c & 63;
          const size_t idx = ((size_t)(bb * 16 + h) * 2048 + t) * 64 + d;
          const int sec = nn >> 10;
          if (sec == 0) {
            Qb[idx] = f2bf(v * QSCALE);
          } else if (sec == 1) {
            outK[idx] = v; Kb[idx] = f2bf(v);
          } else {
            outV[idx] = v; Vb[idx] = f2bf(v);
          }
        }
      }
    }
  }
}

// ---------------- flash attention (round-10 version, verbatim) ----------------
// Grid 1024 (one q-tile each), XCD-pinned (id%8 == bh%8), long-tiles-first.
// S^T = mfma(K,Q) in exp2 domain (Q pre-scaled by 0.125*log2e).
// Defer-max (THR=8); cvt_pk P-pack; K via swizzled global_load_lds (dbuf);
// V^T reg-staged (issue-early/write-late); s_setprio around MFMA clusters.

__global__ __launch_bounds__(256) void attn_kernel(
    const ushort_t* __restrict__ Qb, const ushort_t* __restrict__ Kb,
    const ushort_t* __restrict__ Vb, ushort_t* __restrict__ Yb) {
  __shared__ __align__(16) ushort_t Ks[2][64 * 64];   // K [t][d], chunk-swizzled
  __shared__ __align__(16) ushort_t Vt[2][64 * 72];   // V^T [d][t], swizzled
  __shared__ __align__(16) ushort_t Pl[4 * 16 * 72];  // per-wave P^T' [q][t], swizzled
  const int id = blockIdx.x;
  const int xcd = id & 7, win = id >> 3;
  const int qt = 31 - (win >> 2);     // longest blocks first
  const int bh = xcd + 8 * (win & 3);
  const int b = bh >> 4, h = bh & 15;
  const int tid = threadIdx.x, w = tid >> 6, lane = tid & 63;
  const int l15 = lane & 15, lhi = lane >> 4;
  const int swzP = 2 * (l15 & 3);
  const size_t base = (size_t)bh * 2048 * 64;
  const float NEG_INF = -__builtin_inff();
  ushort_t* myP = &Pl[w * 16 * 72];

  // V-staging thread geometry (per it: t0 = even row, 4 d's)
  const int vd0 = (tid & 15) * 4;
  const int vt0b = (tid >> 4) * 2;

  const int nkt = qt + 1;

  // Q fragments (B-operand): lane holds Q[q = w*16+l15][d = kk*32+lhi*8 ..]
  ushort8 qf[2];
  {
    const size_t qrow = base + (size_t)(qt * 64 + w * 16 + l15) * 64;
    qf[0] = *(const ushort8*)&Qb[qrow + lhi * 8];
    qf[1] = *(const ushort8*)&Qb[qrow + 32 + lhi * 8];
  }
  float m_s = NEG_INF, l_s = 0.f;
  f32x4 o[4] = {};

  // prologue: stage tile 0 into buf 0
  {
#pragma unroll
    for (int it = 0; it < 2; ++it) {
      const int chunk = tid + it * 256;
      const int row = chunk >> 3, g = chunk & 7;
      const int sg = g ^ (row & 7);
      GLOAD_LDS16(Kb + base + (size_t)row * 64 + sg * 8, &Ks[0][chunk * 8]);
    }
#pragma unroll
    for (int it = 0; it < 2; ++it) {
      const int t0 = vt0b + it * 32;
      const ushort_t* vp = Vb + base + (size_t)t0 * 64 + vd0;
      u64_t a = *(const u64_t*)vp;
      u64_t c = *(const u64_t*)(vp + 64);
      us4 av = __builtin_bit_cast(us4, a);
      us4 cv = __builtin_bit_cast(us4, c);
#pragma unroll
      for (int i = 0; i < 4; ++i) {
        const int d = vd0 + i;
        const int scg = (t0 >> 3) ^ ((d >> 3) & 7);
        unsigned int wv = (unsigned int)av[i] | ((unsigned int)cv[i] << 16);
        *(unsigned int*)&Vt[0][d * 72 + scg * 8 + (t0 & 7)] = wv;
      }
    }
  }
  __syncthreads();

  for (int kt = 0; kt < nkt; ++kt) {
    const int cur = kt & 1, nxt = cur ^ 1;
    const bool pf = (kt + 1 < nkt);
    u64_t va[2], vc[2];
    if (pf) {
      const size_t tb = base + (size_t)(kt + 1) * 64 * 64;
#pragma unroll
      for (int it = 0; it < 2; ++it) {
        const int chunk = tid + it * 256;
        const int row = chunk >> 3, g = chunk & 7;
        const int sg = g ^ (row & 7);
        GLOAD_LDS16(Kb + tb + (size_t)row * 64 + sg * 8, &Ks[nxt][chunk * 8]);
      }
#pragma unroll
      for (int it = 0; it < 2; ++it) {
        const int t0 = vt0b + it * 32;
        const ushort_t* vp = Vb + tb + (size_t)t0 * 64 + vd0;
        va[it] = *(const u64_t*)vp;
        vc[it] = *(const u64_t*)(vp + 64);
      }
    }

    // S^T = mfma(K, Q): s[j] rows t = j*16+lhi*4+r, col q = w*16+l15
    f32x4 s[4] = {};
    __builtin_amdgcn_s_setprio(1);
#pragma unroll
    for (int kk = 0; kk < 2; ++kk) {
#pragma unroll
      for (int j = 0; j < 4; ++j) {
        const int g = (kk * 4 + lhi) ^ (l15 & 7);
        ushort8 kb = *(const ushort8*)&Ks[cur][(j * 16 + l15) * 64 + g * 8];
        s[j] = mfma16(kb, qf[kk], s[j]);
      }
    }
    __builtin_amdgcn_s_setprio(0);
    // causal mask (diagonal tile only); S already in exp2 domain
    const int qloc = w * 16 + l15;
    if (kt == qt) {
#pragma unroll
      for (int j = 0; j < 4; ++j)
#pragma unroll
        for (int r = 0; r < 4; ++r)
          if ((j * 16 + lhi * 4 + r) > qloc) s[j][r] = NEG_INF;
    }

    // in-lane softmax for q-row l15 (partials across lhi group)
    float pmax = s[0][0];
#pragma unroll
    for (int j = 0; j < 4; ++j)
#pragma unroll
      for (int r = 0; r < 4; ++r) pmax = fmaxf(pmax, s[j][r]);
    pmax = fmaxf(pmax, __shfl_xor(pmax, 16));
    pmax = fmaxf(pmax, __shfl_xor(pmax, 32));
    // defer-max: only rescale when the running max grew by > 8 (P <= 2^8)
    if (__any(pmax - m_s > 8.0f)) {
      const float mnew = fmaxf(m_s, pmax);
      const float al = exp2v(m_s - mnew);
      m_s = mnew;
      l_s *= al;
#pragma unroll
      for (int df = 0; df < 4; ++df)
#pragma unroll
        for (int r = 0; r < 4; ++r) o[df][r] *= al;
    }
    float rsum = 0.f;
#pragma unroll
    for (int j = 0; j < 4; ++j)
#pragma unroll
      for (int r = 0; r < 4; ++r) {
        const float pe = exp2v(s[j][r] - m_s);
        s[j][r] = pe;
        rsum += pe;
      }
    rsum += __shfl_xor(rsum, 16);
    rsum += __shfl_xor(rsum, 32);
    l_s += rsum;

    // P^T pack -> LDS (wave-private, swizzled b64 writes, cvt_pk)
#pragma unroll
    for (int j = 0; j < 4; ++j) {
      const unsigned int w0 = cvtpk(s[j][0], s[j][1]);
      const unsigned int w1 = cvtpk(s[j][2], s[j][3]);
      const u64_t dw = (u64_t)w0 | ((u64_t)w1 << 32);
      const int cg = j * 2 + (lhi >> 1);
      *(u64_t*)&myP[l15 * 72 + ((cg ^ swzP) << 3) + ((lhi & 1) << 2)] = dw;
    }

    // O^T += mfma(V^T-frag, P^T-frag)
    __builtin_amdgcn_s_setprio(1);
#pragma unroll
    for (int kk = 0; kk < 2; ++kk) {
      ushort8 pa = *(const ushort8*)&myP[l15 * 72 + (((kk * 4 + lhi) ^ swzP) << 3)];
#pragma unroll
      for (int df = 0; df < 4; ++df) {
        const int r = df * 16 + l15;
        const int g = (kk * 4 + lhi) ^ ((r >> 3) & 7);
        ushort8 vb = *(const ushort8*)&Vt[cur][r * 72 + g * 8];
        o[df] = mfma16(vb, pa, o[df]);
      }
    }
    __builtin_amdgcn_s_setprio(0);

    // write-late: V^T for next tile
    if (pf) {
#pragma unroll
      for (int it = 0; it < 2; ++it) {
        const int t0 = vt0b + it * 32;
        us4 av = __builtin_bit_cast(us4, va[it]);
        us4 cv = __builtin_bit_cast(us4, vc[it]);
#pragma unroll
        for (int i = 0; i < 4; ++i) {
          const int d = vd0 + i;
          const int scg = (t0 >> 3) ^ ((d >> 3) & 7);
          unsigned int wv = (unsigned int)av[i] | ((unsigned int)cv[i] << 16);
          *(unsigned int*)&Vt[nxt][d * 72 + scg * 8 + (t0 & 7)] = wv;
        }
      }
    }
    __syncthreads();
  }

  // epilogue: lane holds O^T[d = df*16+lhi*4+r][q = w*16+l15]
  const float inv = 1.0f / l_s;
  const size_t yrow = (size_t)(b * 2048 + qt * 64 + w * 16 + l15) * 1024 + h * 64;
#pragma unroll
  for (int df = 0; df < 4; ++df) {
    us4 ov;
#pragma unroll
    for (int r = 0; r < 4; ++r) ov[r] = f2bf(o[df][r] * inv);
    *(us4*)&Yb[yrow + df * 16 + lhi * 4] = ov;
  }
}

// ---------------- launch ----------------

extern "C" void kernel_launch(void* const* d_in, const int* in_sizes, int n_in,
                              void* d_out, int out_size, void* d_ws, size_t ws_size,
                              hipStream_t stream) {
  const float* x      = (const float*)d_in[0];
  const float* W_kqv  = (const float*)d_in[1];
  const float* b_kqv  = (const float*)d_in[2];
  const float* W_proj = (const float*)d_in[3];
  const float* b_proj = (const float*)d_in[4];
  float* out  = (float*)d_out;          // [B,T,C] fp32
  float* outK = out + 4194304;          // [B,H,T,D] fp32
  float* outV = out + 8388608;          // [B,H,T,D] fp32

  char* ws = (char*)d_ws;
  ushort_t* Xb  = (ushort_t*)(ws);
  ushort_t* Wkt = (ushort_t*)(ws + ((size_t)8 << 20));
  ushort_t* Wpt = (ushort_t*)(ws + ((size_t)14 << 20));
  ushort_t* Qb  = (ushort_t*)(ws + ((size_t)16 << 20));
  ushort_t* Kb  = (ushort_t*)(ws + ((size_t)24 << 20));
  ushort_t* Vb  = (ushort_t*)(ws + ((size_t)32 << 20));
  ushort_t* Yb  = Xb;  // Xb dead after QKV GEMM

  prep_kernel<<<6144, 256, 0, stream>>>(x, W_kqv, W_proj, Xb, Wkt, Wpt);
  gemm_bt_kernel<<<dim3(24, 32), 256, 0, stream>>>(
      Xb, Wkt, b_kqv, nullptr, outK, outV, Qb, Kb, Vb, 4096, 3072, 1024, 1);
  attn_kernel<<<1024, 256, 0, stream>>>(Qb, Kb, Vb, Yb);
  gemm_bt_kernel<<<dim3(8, 32), 256, 0, stream>>>(
      Yb, Wpt, b_proj, out, nullptr, nullptr, nullptr, nullptr, nullptr,
      4096, 1024, 1024, 0);
}

// Round 14
// 110.294 us; speedup vs baseline: 1.3414x; 1.0382x over previous
//
#include <hip/hip_runtime.h>

// Workspace layout (40 MB total):
//   [0,  8M)  Xb  bf16 [4096][1024]   (reused as Yb after QKV GEMM)
//   [8, 14M)  Wkqv_t bf16 [3072][1024]
//   [14,16M)  Wproj_t bf16 [1024][1024]
//   [16,24M)  Qb bf16 [B,H,T,D]  (pre-scaled by 0.125*log2e)
//   [24,32M)  Kb bf16 [B,H,T,D]
//   [32,40M)  Vb bf16 [B,H,T,D]

#define DEVI __device__ __forceinline__

typedef unsigned short ushort_t;
typedef unsigned long long u64_t;
typedef __attribute__((ext_vector_type(4))) unsigned short us4;
typedef __attribute__((ext_vector_type(8))) unsigned short ushort8;
typedef __attribute__((ext_vector_type(4))) float f32x4;
typedef __attribute__((ext_vector_type(8))) __bf16 bf16x8;

DEVI unsigned short f2bf(float f) {
  union { float f; unsigned int u; } c; c.f = f;
  unsigned int u = c.u;
  unsigned int r = (u + 0x7FFFu + ((u >> 16) & 1u)) >> 16;
  return (unsigned short)r;
}

// exp2 via raw v_exp_f32 (1 VALU trans op; s_nop covers the RAW hazard)
DEVI float exp2v(float x) {
  float r;
  asm("v_exp_f32 %0, %1\n\ts_nop 0" : "=v"(r) : "v"(x));
  return r;
}

// pack 2 fp32 -> 2 bf16 (RNE) in one instruction
DEVI unsigned int cvtpk(float lo, float hi) {
  unsigned int r;
  asm("v_cvt_pk_bf16_f32 %0, %1, %2" : "=v"(r) : "v"(lo), "v"(hi));
  return r;
}

DEVI f32x4 mfma16(ushort8 a, ushort8 b, f32x4 c) {
  return __builtin_amdgcn_mfma_f32_16x16x32_bf16(
      __builtin_bit_cast(bf16x8, a), __builtin_bit_cast(bf16x8, b), c, 0, 0, 0);
}

typedef const __attribute__((address_space(1))) void* gptr_t;
typedef __attribute__((address_space(3))) void* lptr_t;
#define GLOAD_LDS16(g, l) \
  __builtin_amdgcn_global_load_lds((gptr_t)(g), (lptr_t)(l), 16, 0, 0)

DEVI void bar() {
  asm volatile("" ::: "memory");
  __builtin_amdgcn_s_barrier();
  asm volatile("" ::: "memory");
}
#define VMCNT(n) asm volatile("s_waitcnt vmcnt(" #n ")" ::: "memory")

// ---------------- fused prep kernel ----------------
// blocks [0,2048): cast x -> Xb (bf16)
// blocks [2048,5120): transpose+cast W_kqv -> Wkt [3072][1024]
// blocks [5120,6144): transpose+cast W_proj -> Wpt [1024][1024]

__global__ void prep_kernel(const float* __restrict__ x,
                            const float* __restrict__ Wk,
                            const float* __restrict__ Wp,
                            ushort_t* __restrict__ Xb,
                            ushort_t* __restrict__ Wkt,
                            ushort_t* __restrict__ Wpt) {
  __shared__ float tile[32][33];
  const int id = blockIdx.x, tid = threadIdx.x;
  if (id < 2048) {
    const int i = id * 256 + tid;
    const f32x4* p = (const f32x4*)x;
    f32x4 a = p[2 * i], b = p[2 * i + 1];
    ushort8 o;
    o[0] = f2bf(a[0]); o[1] = f2bf(a[1]); o[2] = f2bf(a[2]); o[3] = f2bf(a[3]);
    o[4] = f2bf(b[0]); o[5] = f2bf(b[1]); o[6] = f2bf(b[2]); o[7] = f2bf(b[3]);
    ((ushort8*)Xb)[i] = o;
    return;
  }
  const float* in;
  ushort_t* outp;
  int R = 1024, Cin, bx, by;
  if (id < 5120) {
    const int jid = id - 2048;
    bx = jid % 96; by = jid / 96; in = Wk; outp = Wkt; Cin = 3072;
  } else {
    const int jid = id - 5120;
    bx = jid % 32; by = jid / 32; in = Wp; outp = Wpt; Cin = 1024;
  }
  const int c0 = bx * 32, r0 = by * 32;
  const int tx = tid & 31, ty = tid >> 5;
#pragma unroll
  for (int it = 0; it < 4; ++it)
    tile[ty + it * 8][tx] = in[(size_t)(r0 + ty + it * 8) * Cin + c0 + tx];
  __syncthreads();
#pragma unroll
  for (int it = 0; it < 4; ++it)
    outp[(size_t)(c0 + ty + it * 8) * R + r0 + tx] = f2bf(tile[tx][ty + it * 8]);
}

// ---------------- QKV GEMM: 128x128, m97 structure ----------------
// mode 1 epilogue: scatter q/k/v; Qb pre-scaled by 0.125*log2e for attn.

__global__ __launch_bounds__(256) void gemm_bt_kernel(
    const ushort_t* __restrict__ A, const ushort_t* __restrict__ Bt,
    const float* __restrict__ bias, float* __restrict__ outF,
    float* __restrict__ outK, float* __restrict__ outV,
    ushort_t* __restrict__ Qb, ushort_t* __restrict__ Kb, ushort_t* __restrict__ Vb,
    int M, int N, int K, int mode) {
  __shared__ __align__(16) ushort_t As[128 * 64];
  __shared__ __align__(16) ushort_t Bs[128 * 64];
  const int tid = threadIdx.x;
  const int w = tid >> 6, lane = tid & 63;
  const int wr = w >> 1, wc = w & 1;
  const int nbx = gridDim.x;
  const int nwg = nbx * gridDim.y;
  const int orig = blockIdx.x + nbx * blockIdx.y;
  const int tile = (orig & 7) * (nwg >> 3) + (orig >> 3);
  const int bx = tile % nbx, by = tile / nbx;
  const int m0 = by * 128, n0 = bx * 128;
  const int l15 = lane & 15, lhi = lane >> 4;
  const int rowA = lane >> 3;
  const int sgc = (((lane & 7) ^ ((lane >> 3) & 7)) << 3);

  f32x4 acc[4][4] = {};

  const int nk = K >> 6;
  for (int kt = 0; kt < nk; ++kt) {
    const size_t k0 = (size_t)kt << 6;
    if (kt) bar();
#pragma unroll
    for (int it = 0; it < 4; ++it) {
      const int rbase = (w * 4 + it) * 8;
      GLOAD_LDS16(A + (size_t)(m0 + rbase + rowA) * K + k0 + sgc, &As[rbase * 64]);
      GLOAD_LDS16(Bt + (size_t)(n0 + rbase + rowA) * K + k0 + sgc, &Bs[rbase * 64]);
    }
    VMCNT(0);
    bar();
#pragma unroll
    for (int kk = 0; kk < 2; ++kk) {
      const int gof = (((kk * 4 + lhi) ^ (l15 & 7)) << 3);
      ushort8 a[4], b[4];
#pragma unroll
      for (int i = 0; i < 4; ++i)
        a[i] = *(const ushort8*)&As[(wr * 64 + i * 16 + l15) * 64 + gof];
#pragma unroll
      for (int j = 0; j < 4; ++j)
        b[j] = *(const ushort8*)&Bs[(wc * 64 + j * 16 + l15) * 64 + gof];
#pragma unroll
      for (int i = 0; i < 4; ++i)
#pragma unroll
        for (int j = 0; j < 4; ++j) acc[i][j] = mfma16(a[i], b[j], acc[i][j]);
    }
  }

  const float QSCALE = 0.18033688011112042f;  // 0.125 * log2(e)
#pragma unroll
  for (int i = 0; i < 4; ++i) {
#pragma unroll
    for (int j = 0; j < 4; ++j) {
      const int nn = n0 + wc * 64 + j * 16 + l15;
      const float bv = bias[nn];
#pragma unroll
      for (int r = 0; r < 4; ++r) {
        const int mm = m0 + wr * 64 + i * 16 + lhi * 4 + r;
        const float v = acc[i][j][r] + bv;
        if (mode == 0) {
          outF[(size_t)mm * N + nn] = v;
        } else {
          const int bb = mm >> 11, t = mm & 2047;
          const int c = nn & 1023, h = c >> 6, d = c & 63;
          const size_t idx = ((size_t)(bb * 16 + h) * 2048 + t) * 64 + d;
          const int sec = nn >> 10;
          if (sec == 0) {
            Qb[idx] = f2bf(v * QSCALE);
          } else if (sec == 1) {
            outK[idx] = v; Kb[idx] = f2bf(v);
          } else {
            outV[idx] = v; Vb[idx] = f2bf(v);
          }
        }
      }
    }
  }
}

// ---------------- proj GEMM: 64x128 tiles (512 blocks -> 2 blocks/CU) ----------------
// Same m97 loop + swizzles; wave tile 32x64 (acc[2][4]); 24 KB LDS.
// Staging rows: As (w*2+it)*8 + lane>>3 covers 0..63 once; swizzle key row&7
// == (lane>>3)&7 on both write (sgc source) and read (gof) sides.

__global__ __launch_bounds__(256) void gemm_bt64_kernel(
    const ushort_t* __restrict__ A, const ushort_t* __restrict__ Bt,
    const float* __restrict__ bias, float* __restrict__ outF,
    int M, int N, int K) {
  __shared__ __align__(16) ushort_t As[64 * 64];
  __shared__ __align__(16) ushort_t Bs[128 * 64];
  const int tid = threadIdx.x;
  const int w = tid >> 6, lane = tid & 63;
  const int wr = w >> 1, wc = w & 1;
  const int nbx = gridDim.x;
  const int nwg = nbx * gridDim.y;
  const int orig = blockIdx.x + nbx * blockIdx.y;
  const int tile = (orig & 7) * (nwg >> 3) + (orig >> 3);
  const int bx = tile % nbx, by = tile / nbx;
  const int m0 = by * 64, n0 = bx * 128;
  const int l15 = lane & 15, lhi = lane >> 4;
  const int rowA = lane >> 3;
  const int sgc = (((lane & 7) ^ ((lane >> 3) & 7)) << 3);

  f32x4 acc[2][4] = {};

  const int nk = K >> 6;
  for (int kt = 0; kt < nk; ++kt) {
    const size_t k0 = (size_t)kt << 6;
    if (kt) bar();
#pragma unroll
    for (int it = 0; it < 2; ++it) {
      const int rbase = (w * 2 + it) * 8;  // A: 64 rows
      GLOAD_LDS16(A + (size_t)(m0 + rbase + rowA) * K + k0 + sgc, &As[rbase * 64]);
    }
#pragma unroll
    for (int it = 0; it < 4; ++it) {
      const int rbase = (w * 4 + it) * 8;  // B: 128 rows
      GLOAD_LDS16(Bt + (size_t)(n0 + rbase + rowA) * K + k0 + sgc, &Bs[rbase * 64]);
    }
    VMCNT(0);
    bar();
#pragma unroll
    for (int kk = 0; kk < 2; ++kk) {
      const int gof = (((kk * 4 + lhi) ^ (l15 & 7)) << 3);
      ushort8 a[2], b[4];
#pragma unroll
      for (int i = 0; i < 2; ++i)
        a[i] = *(const ushort8*)&As[(wr * 32 + i * 16 + l15) * 64 + gof];
#pragma unroll
      for (int j = 0; j < 4; ++j)
        b[j] = *(const ushort8*)&Bs[(wc * 64 + j * 16 + l15) * 64 + gof];
#pragma unroll
      for (int i = 0; i < 2; ++i)
#pragma unroll
        for (int j = 0; j < 4; ++j) acc[i][j] = mfma16(a[i], b[j], acc[i][j]);
    }
  }

#pragma unroll
  for (int i = 0; i < 2; ++i) {
#pragma unroll
    for (int j = 0; j < 4; ++j) {
      const int nn = n0 + wc * 64 + j * 16 + l15;
      const float bv = bias[nn];
#pragma unroll
      for (int r = 0; r < 4; ++r) {
        const int mm = m0 + wr * 32 + i * 16 + lhi * 4 + r;
        outF[(size_t)mm * N + nn] = acc[i][j][r] + bv;
      }
    }
  }
}

// ---------------- flash attention (round-10/13 version, verbatim) ----------------
// Grid 1024 (one q-tile each), XCD-pinned (id%8 == bh%8), long-tiles-first.
// S^T = mfma(K,Q) in exp2 domain (Q pre-scaled by 0.125*log2e).
// Defer-max (THR=8); cvt_pk P-pack; K via swizzled global_load_lds (dbuf);
// V^T reg-staged (issue-early/write-late); s_setprio around MFMA clusters.

__global__ __launch_bounds__(256) void attn_kernel(
    const ushort_t* __restrict__ Qb, const ushort_t* __restrict__ Kb,
    const ushort_t* __restrict__ Vb, ushort_t* __restrict__ Yb) {
  __shared__ __align__(16) ushort_t Ks[2][64 * 64];   // K [t][d], chunk-swizzled
  __shared__ __align__(16) ushort_t Vt[2][64 * 72];   // V^T [d][t], swizzled
  __shared__ __align__(16) ushort_t Pl[4 * 16 * 72];  // per-wave P^T' [q][t], swizzled
  const int id = blockIdx.x;
  const int xcd = id & 7, win = id >> 3;
  const int qt = 31 - (win >> 2);     // longest blocks first
  const int bh = xcd + 8 * (win & 3);
  const int b = bh >> 4, h = bh & 15;
  const int tid = threadIdx.x, w = tid >> 6, lane = tid & 63;
  const int l15 = lane & 15, lhi = lane >> 4;
  const int swzP = 2 * (l15 & 3);
  const size_t base = (size_t)bh * 2048 * 64;
  const float NEG_INF = -__builtin_inff();
  ushort_t* myP = &Pl[w * 16 * 72];

  // V-staging thread geometry (per it: t0 = even row, 4 d's)
  const int vd0 = (tid & 15) * 4;
  const int vt0b = (tid >> 4) * 2;

  const int nkt = qt + 1;

  // Q fragments (B-operand): lane holds Q[q = w*16+l15][d = kk*32+lhi*8 ..]
  ushort8 qf[2];
  {
    const size_t qrow = base + (size_t)(qt * 64 + w * 16 + l15) * 64;
    qf[0] = *(const ushort8*)&Qb[qrow + lhi * 8];
    qf[1] = *(const ushort8*)&Qb[qrow + 32 + lhi * 8];
  }
  float m_s = NEG_INF, l_s = 0.f;
  f32x4 o[4] = {};

  // prologue: stage tile 0 into buf 0
  {
#pragma unroll
    for (int it = 0; it < 2; ++it) {
      const int chunk = tid + it * 256;
      const int row = chunk >> 3, g = chunk & 7;
      const int sg = g ^ (row & 7);
      GLOAD_LDS16(Kb + base + (size_t)row * 64 + sg * 8, &Ks[0][chunk * 8]);
    }
#pragma unroll
    for (int it = 0; it < 2; ++it) {
      const int t0 = vt0b + it * 32;
      const ushort_t* vp = Vb + base + (size_t)t0 * 64 + vd0;
      u64_t a = *(const u64_t*)vp;
      u64_t c = *(const u64_t*)(vp + 64);
      us4 av = __builtin_bit_cast(us4, a);
      us4 cv = __builtin_bit_cast(us4, c);
#pragma unroll
      for (int i = 0; i < 4; ++i) {
        const int d = vd0 + i;
        const int scg = (t0 >> 3) ^ ((d >> 3) & 7);
        unsigned int wv = (unsigned int)av[i] | ((unsigned int)cv[i] << 16);
        *(unsigned int*)&Vt[0][d * 72 + scg * 8 + (t0 & 7)] = wv;
      }
    }
  }
  __syncthreads();

  for (int kt = 0; kt < nkt; ++kt) {
    const int cur = kt & 1, nxt = cur ^ 1;
    const bool pf = (kt + 1 < nkt);
    u64_t va[2], vc[2];
    if (pf) {
      const size_t tb = base + (size_t)(kt + 1) * 64 * 64;
#pragma unroll
      for (int it = 0; it < 2; ++it) {
        const int chunk = tid + it * 256;
        const int row = chunk >> 3, g = chunk & 7;
        const int sg = g ^ (row & 7);
        GLOAD_LDS16(Kb + tb + (size_t)row * 64 + sg * 8, &Ks[nxt][chunk * 8]);
      }
#pragma unroll
      for (int it = 0; it < 2; ++it) {
        const int t0 = vt0b + it * 32;
        const ushort_t* vp = Vb + tb + (size_t)t0 * 64 + vd0;
        va[it] = *(const u64_t*)vp;
        vc[it] = *(const u64_t*)(vp + 64);
      }
    }

    // S^T = mfma(K, Q): s[j] rows t = j*16+lhi*4+r, col q = w*16+l15
    f32x4 s[4] = {};
    __builtin_amdgcn_s_setprio(1);
#pragma unroll
    for (int kk = 0; kk < 2; ++kk) {
#pragma unroll
      for (int j = 0; j < 4; ++j) {
        const int g = (kk * 4 + lhi) ^ (l15 & 7);
        ushort8 kb = *(const ushort8*)&Ks[cur][(j * 16 + l15) * 64 + g * 8];
        s[j] = mfma16(kb, qf[kk], s[j]);
      }
    }
    __builtin_amdgcn_s_setprio(0);
    // causal mask (diagonal tile only); S already in exp2 domain
    const int qloc = w * 16 + l15;
    if (kt == qt) {
#pragma unroll
      for (int j = 0; j < 4; ++j)
#pragma unroll
        for (int r = 0; r < 4; ++r)
          if ((j * 16 + lhi * 4 + r) > qloc) s[j][r] = NEG_INF;
    }

    // in-lane softmax for q-row l15 (partials across lhi group)
    float pmax = s[0][0];
#pragma unroll
    for (int j = 0; j < 4; ++j)
#pragma unroll
      for (int r = 0; r < 4; ++r) pmax = fmaxf(pmax, s[j][r]);
    pmax = fmaxf(pmax, __shfl_xor(pmax, 16));
    pmax = fmaxf(pmax, __shfl_xor(pmax, 32));
    // defer-max: only rescale when the running max grew by > 8 (P <= 2^8)
    if (__any(pmax - m_s > 8.0f)) {
      const float mnew = fmaxf(m_s, pmax);
      const float al = exp2v(m_s - mnew);
      m_s = mnew;
      l_s *= al;
#pragma unroll
      for (int df = 0; df < 4; ++df)
#pragma unroll
        for (int r = 0; r < 4; ++r) o[df][r] *= al;
    }
    float rsum = 0.f;
#pragma unroll
    for (int j = 0; j < 4; ++j)
#pragma unroll
      for (int r = 0; r < 4; ++r) {
        const float pe = exp2v(s[j][r] - m_s);
        s[j][r] = pe;
        rsum += pe;
      }
    rsum += __shfl_xor(rsum, 16);
    rsum += __shfl_xor(rsum, 32);
    l_s += rsum;

    // P^T pack -> LDS (wave-private, swizzled b64 writes, cvt_pk)
#pragma unroll
    for (int j = 0; j < 4; ++j) {
      const unsigned int w0 = cvtpk(s[j][0], s[j][1]);
      const unsigned int w1 = cvtpk(s[j][2], s[j][3]);
      const u64_t dw = (u64_t)w0 | ((u64_t)w1 << 32);
      const int cg = j * 2 + (lhi >> 1);
      *(u64_t*)&myP[l15 * 72 + ((cg ^ swzP) << 3) + ((lhi & 1) << 2)] = dw;
    }

    // O^T += mfma(V^T-frag, P^T-frag)
    __builtin_amdgcn_s_setprio(1);
#pragma unroll
    for (int kk = 0; kk < 2; ++kk) {
      ushort8 pa = *(const ushort8*)&myP[l15 * 72 + (((kk * 4 + lhi) ^ swzP) << 3)];
#pragma unroll
      for (int df = 0; df < 4; ++df) {
        const int r = df * 16 + l15;
        const int g = (kk * 4 + lhi) ^ ((r >> 3) & 7);
        ushort8 vb = *(const ushort8*)&Vt[cur][r * 72 + g * 8];
        o[df] = mfma16(vb, pa, o[df]);
      }
    }
    __builtin_amdgcn_s_setprio(0);

    // write-late: V^T for next tile
    if (pf) {
#pragma unroll
      for (int it = 0; it < 2; ++it) {
        const int t0 = vt0b + it * 32;
        us4 av = __builtin_bit_cast(us4, va[it]);
        us4 cv = __builtin_bit_cast(us4, vc[it]);
#pragma unroll
        for (int i = 0; i < 4; ++i) {
          const int d = vd0 + i;
          const int scg = (t0 >> 3) ^ ((d >> 3) & 7);
          unsigned int wv = (unsigned int)av[i] | ((unsigned int)cv[i] << 16);
          *(unsigned int*)&Vt[nxt][d * 72 + scg * 8 + (t0 & 7)] = wv;
        }
      }
    }
    __syncthreads();
  }

  // epilogue: lane holds O^T[d = df*16+lhi*4+r][q = w*16+l15]
  const float inv = 1.0f / l_s;
  const size_t yrow = (size_t)(b * 2048 + qt * 64 + w * 16 + l15) * 1024 + h * 64;
#pragma unroll
  for (int df = 0; df < 4; ++df) {
    us4 ov;
#pragma unroll
    for (int r = 0; r < 4; ++r) ov[r] = f2bf(o[df][r] * inv);
    *(us4*)&Yb[yrow + df * 16 + lhi * 4] = ov;
  }
}

// ---------------- launch ----------------

extern "C" void kernel_launch(void* const* d_in, const int* in_sizes, int n_in,
                              void* d_out, int out_size, void* d_ws, size_t ws_size,
                              hipStream_t stream) {
  const float* x      = (const float*)d_in[0];
  const float* W_kqv  = (const float*)d_in[1];
  const float* b_kqv  = (const float*)d_in[2];
  const float* W_proj = (const float*)d_in[3];
  const float* b_proj = (const float*)d_in[4];
  float* out  = (float*)d_out;          // [B,T,C] fp32
  float* outK = out + 4194304;          // [B,H,T,D] fp32
  float* outV = out + 8388608;          // [B,H,T,D] fp32

  char* ws = (char*)d_ws;
  ushort_t* Xb  = (ushort_t*)(ws);
  ushort_t* Wkt = (ushort_t*)(ws + ((size_t)8 << 20));
  ushort_t* Wpt = (ushort_t*)(ws + ((size_t)14 << 20));
  ushort_t* Qb  = (ushort_t*)(ws + ((size_t)16 << 20));
  ushort_t* Kb  = (ushort_t*)(ws + ((size_t)24 << 20));
  ushort_t* Vb  = (ushort_t*)(ws + ((size_t)32 << 20));
  ushort_t* Yb  = Xb;  // Xb dead after QKV GEMM

  prep_kernel<<<6144, 256, 0, stream>>>(x, W_kqv, W_proj, Xb, Wkt, Wpt);
  gemm_bt_kernel<<<dim3(24, 32), 256, 0, stream>>>(
      Xb, Wkt, b_kqv, nullptr, outK, outV, Qb, Kb, Vb, 4096, 3072, 1024, 1);
  attn_kernel<<<1024, 256, 0, stream>>>(Qb, Kb, Vb, Yb);
  gemm_bt64_kernel<<<dim3(8, 64), 256, 0, stream>>>(
      Yb, Wpt, b_proj, out, 4096, 1024, 1024);
}

// Round 15
// 108.804 us; speedup vs baseline: 1.3597x; 1.0137x over previous
//
#include <hip/hip_runtime.h>

// Workspace layout (40 MB total):
//   [0,  8M)  Xb  bf16 [4096][1024]   (reused as Yb after QKV GEMM)
//   [8, 14M)  Wkqv_t bf16 [3072][1024]
//   [14,16M)  Wproj_t bf16 [1024][1024]
//   [16,24M)  Qb bf16 [B,H,T,D]  (pre-scaled by 0.125*log2e)
//   [24,32M)  Kb bf16 [B,H,T,D]
//   [32,40M)  Vb bf16 [B,H,T,D]

#define DEVI __device__ __forceinline__

typedef unsigned short ushort_t;
typedef unsigned long long u64_t;
typedef __attribute__((ext_vector_type(4))) unsigned short us4;
typedef __attribute__((ext_vector_type(8))) unsigned short ushort8;
typedef __attribute__((ext_vector_type(4))) float f32x4;
typedef __attribute__((ext_vector_type(8))) __bf16 bf16x8;

DEVI unsigned short f2bf(float f) {
  union { float f; unsigned int u; } c; c.f = f;
  unsigned int u = c.u;
  unsigned int r = (u + 0x7FFFu + ((u >> 16) & 1u)) >> 16;
  return (unsigned short)r;
}

// exp2 via raw v_exp_f32 (1 VALU trans op; s_nop covers the RAW hazard)
DEVI float exp2v(float x) {
  float r;
  asm("v_exp_f32 %0, %1\n\ts_nop 0" : "=v"(r) : "v"(x));
  return r;
}

// pack 2 fp32 -> 2 bf16 (RNE) in one instruction
DEVI unsigned int cvtpk(float lo, float hi) {
  unsigned int r;
  asm("v_cvt_pk_bf16_f32 %0, %1, %2" : "=v"(r) : "v"(lo), "v"(hi));
  return r;
}

DEVI f32x4 mfma16(ushort8 a, ushort8 b, f32x4 c) {
  return __builtin_amdgcn_mfma_f32_16x16x32_bf16(
      __builtin_bit_cast(bf16x8, a), __builtin_bit_cast(bf16x8, b), c, 0, 0, 0);
}

typedef const __attribute__((address_space(1))) void* gptr_t;
typedef __attribute__((address_space(3))) void* lptr_t;
#define GLOAD_LDS16(g, l) \
  __builtin_amdgcn_global_load_lds((gptr_t)(g), (lptr_t)(l), 16, 0, 0)

DEVI void bar() {
  asm volatile("" ::: "memory");
  __builtin_amdgcn_s_barrier();
  asm volatile("" ::: "memory");
}
#define VMCNT(n) asm volatile("s_waitcnt vmcnt(" #n ")" ::: "memory")

// ---------------- fused prep kernel ----------------
// blocks [0,2048): cast x -> Xb (bf16)
// blocks [2048,5120): transpose+cast W_kqv -> Wkt [3072][1024]
// blocks [5120,6144): transpose+cast W_proj -> Wpt [1024][1024]

__global__ void prep_kernel(const float* __restrict__ x,
                            const float* __restrict__ Wk,
                            const float* __restrict__ Wp,
                            ushort_t* __restrict__ Xb,
                            ushort_t* __restrict__ Wkt,
                            ushort_t* __restrict__ Wpt) {
  __shared__ float tile[32][33];
  const int id = blockIdx.x, tid = threadIdx.x;
  if (id < 2048) {
    const int i = id * 256 + tid;
    const f32x4* p = (const f32x4*)x;
    f32x4 a = p[2 * i], b = p[2 * i + 1];
    ushort8 o;
    o[0] = f2bf(a[0]); o[1] = f2bf(a[1]); o[2] = f2bf(a[2]); o[3] = f2bf(a[3]);
    o[4] = f2bf(b[0]); o[5] = f2bf(b[1]); o[6] = f2bf(b[2]); o[7] = f2bf(b[3]);
    ((ushort8*)Xb)[i] = o;
    return;
  }
  const float* in;
  ushort_t* outp;
  int R = 1024, Cin, bx, by;
  if (id < 5120) {
    const int jid = id - 2048;
    bx = jid % 96; by = jid / 96; in = Wk; outp = Wkt; Cin = 3072;
  } else {
    const int jid = id - 5120;
    bx = jid % 32; by = jid / 32; in = Wp; outp = Wpt; Cin = 1024;
  }
  const int c0 = bx * 32, r0 = by * 32;
  const int tx = tid & 31, ty = tid >> 5;
#pragma unroll
  for (int it = 0; it < 4; ++it)
    tile[ty + it * 8][tx] = in[(size_t)(r0 + ty + it * 8) * Cin + c0 + tx];
  __syncthreads();
#pragma unroll
  for (int it = 0; it < 4; ++it)
    outp[(size_t)(c0 + ty + it * 8) * R + r0 + tx] = f2bf(tile[tx][ty + it * 8]);
}

// ---------------- QKV GEMM: 128x128, m97 structure ----------------
// mode 1 epilogue: scatter q/k/v; Qb pre-scaled by 0.125*log2e for attn.

__global__ __launch_bounds__(256) void gemm_bt_kernel(
    const ushort_t* __restrict__ A, const ushort_t* __restrict__ Bt,
    const float* __restrict__ bias, float* __restrict__ outF,
    float* __restrict__ outK, float* __restrict__ outV,
    ushort_t* __restrict__ Qb, ushort_t* __restrict__ Kb, ushort_t* __restrict__ Vb,
    int M, int N, int K, int mode) {
  __shared__ __align__(16) ushort_t As[128 * 64];
  __shared__ __align__(16) ushort_t Bs[128 * 64];
  const int tid = threadIdx.x;
  const int w = tid >> 6, lane = tid & 63;
  const int wr = w >> 1, wc = w & 1;
  const int nbx = gridDim.x;
  const int nwg = nbx * gridDim.y;
  const int orig = blockIdx.x + nbx * blockIdx.y;
  const int tile = (orig & 7) * (nwg >> 3) + (orig >> 3);
  const int bx = tile % nbx, by = tile / nbx;
  const int m0 = by * 128, n0 = bx * 128;
  const int l15 = lane & 15, lhi = lane >> 4;
  const int rowA = lane >> 3;
  const int sgc = (((lane & 7) ^ ((lane >> 3) & 7)) << 3);

  f32x4 acc[4][4] = {};

  const int nk = K >> 6;
  for (int kt = 0; kt < nk; ++kt) {
    const size_t k0 = (size_t)kt << 6;
    if (kt) bar();
#pragma unroll
    for (int it = 0; it < 4; ++it) {
      const int rbase = (w * 4 + it) * 8;
      GLOAD_LDS16(A + (size_t)(m0 + rbase + rowA) * K + k0 + sgc, &As[rbase * 64]);
      GLOAD_LDS16(Bt + (size_t)(n0 + rbase + rowA) * K + k0 + sgc, &Bs[rbase * 64]);
    }
    VMCNT(0);
    bar();
#pragma unroll
    for (int kk = 0; kk < 2; ++kk) {
      const int gof = (((kk * 4 + lhi) ^ (l15 & 7)) << 3);
      ushort8 a[4], b[4];
#pragma unroll
      for (int i = 0; i < 4; ++i)
        a[i] = *(const ushort8*)&As[(wr * 64 + i * 16 + l15) * 64 + gof];
#pragma unroll
      for (int j = 0; j < 4; ++j)
        b[j] = *(const ushort8*)&Bs[(wc * 64 + j * 16 + l15) * 64 + gof];
#pragma unroll
      for (int i = 0; i < 4; ++i)
#pragma unroll
        for (int j = 0; j < 4; ++j) acc[i][j] = mfma16(a[i], b[j], acc[i][j]);
    }
  }

  const float QSCALE = 0.18033688011112042f;  // 0.125 * log2(e)
#pragma unroll
  for (int i = 0; i < 4; ++i) {
#pragma unroll
    for (int j = 0; j < 4; ++j) {
      const int nn = n0 + wc * 64 + j * 16 + l15;
      const float bv = bias[nn];
#pragma unroll
      for (int r = 0; r < 4; ++r) {
        const int mm = m0 + wr * 64 + i * 16 + lhi * 4 + r;
        const float v = acc[i][j][r] + bv;
        if (mode == 0) {
          outF[(size_t)mm * N + nn] = v;
        } else {
          const int bb = mm >> 11, t = mm & 2047;
          const int c = nn & 1023, h = c >> 6, d = c & 63;
          const size_t idx = ((size_t)(bb * 16 + h) * 2048 + t) * 64 + d;
          const int sec = nn >> 10;
          if (sec == 0) {
            Qb[idx] = f2bf(v * QSCALE);
          } else if (sec == 1) {
            outK[idx] = v; Kb[idx] = f2bf(v);
          } else {
            outV[idx] = v; Vb[idx] = f2bf(v);
          }
        }
      }
    }
  }
}

// ---------------- proj GEMM: 64x128 tiles (512 blocks -> 2 blocks/CU) ----------------

__global__ __launch_bounds__(256) void gemm_bt64_kernel(
    const ushort_t* __restrict__ A, const ushort_t* __restrict__ Bt,
    const float* __restrict__ bias, float* __restrict__ outF,
    int M, int N, int K) {
  __shared__ __align__(16) ushort_t As[64 * 64];
  __shared__ __align__(16) ushort_t Bs[128 * 64];
  const int tid = threadIdx.x;
  const int w = tid >> 6, lane = tid & 63;
  const int wr = w >> 1, wc = w & 1;
  const int nbx = gridDim.x;
  const int nwg = nbx * gridDim.y;
  const int orig = blockIdx.x + nbx * blockIdx.y;
  const int tile = (orig & 7) * (nwg >> 3) + (orig >> 3);
  const int bx = tile % nbx, by = tile / nbx;
  const int m0 = by * 64, n0 = bx * 128;
  const int l15 = lane & 15, lhi = lane >> 4;
  const int rowA = lane >> 3;
  const int sgc = (((lane & 7) ^ ((lane >> 3) & 7)) << 3);

  f32x4 acc[2][4] = {};

  const int nk = K >> 6;
  for (int kt = 0; kt < nk; ++kt) {
    const size_t k0 = (size_t)kt << 6;
    if (kt) bar();
#pragma unroll
    for (int it = 0; it < 2; ++it) {
      const int rbase = (w * 2 + it) * 8;  // A: 64 rows
      GLOAD_LDS16(A + (size_t)(m0 + rbase + rowA) * K + k0 + sgc, &As[rbase * 64]);
    }
#pragma unroll
    for (int it = 0; it < 4; ++it) {
      const int rbase = (w * 4 + it) * 8;  // B: 128 rows
      GLOAD_LDS16(Bt + (size_t)(n0 + rbase + rowA) * K + k0 + sgc, &Bs[rbase * 64]);
    }
    VMCNT(0);
    bar();
#pragma unroll
    for (int kk = 0; kk < 2; ++kk) {
      const int gof = (((kk * 4 + lhi) ^ (l15 & 7)) << 3);
      ushort8 a[2], b[4];
#pragma unroll
      for (int i = 0; i < 2; ++i)
        a[i] = *(const ushort8*)&As[(wr * 32 + i * 16 + l15) * 64 + gof];
#pragma unroll
      for (int j = 0; j < 4; ++j)
        b[j] = *(const ushort8*)&Bs[(wc * 64 + j * 16 + l15) * 64 + gof];
#pragma unroll
      for (int i = 0; i < 2; ++i)
#pragma unroll
        for (int j = 0; j < 4; ++j) acc[i][j] = mfma16(a[i], b[j], acc[i][j]);
    }
  }

#pragma unroll
  for (int i = 0; i < 2; ++i) {
#pragma unroll
    for (int j = 0; j < 4; ++j) {
      const int nn = n0 + wc * 64 + j * 16 + l15;
      const float bv = bias[nn];
#pragma unroll
      for (int r = 0; r < 4; ++r) {
        const int mm = m0 + wr * 32 + i * 16 + lhi * 4 + r;
        outF[(size_t)mm * N + nn] = acc[i][j][r] + bv;
      }
    }
  }
}

// ---------------- flash attention: 8 waves, 128-row Q-tile ----------------
// Grid 512 blocks x 512 threads. XCD-pinned (id%8 == bh%8), longest-first.
// Per block: q-tile qt (128 rows), nkt = 2*qt+2 KV tiles of 64.
// Staged K/V tile feeds 8 waves (2x amortization vs 4-wave version);
// 3 blocks/CU x 8 waves = 24 waves/CU = 6 waves/SIMD (2x round-14).
// Wave w owns q-rows qt*128 + w*16 + l15. Same swizzles/softmax as round-14.
// Causal: delta = 128*qt + qrow - 64*kt; mask tk > delta. Fully-masked tiles
// (w<4 in last step) produce P=0 via exp2(-inf)=0 -- no divergence at barriers.

__global__ __launch_bounds__(512) void attn_kernel(
    const ushort_t* __restrict__ Qb, const ushort_t* __restrict__ Kb,
    const ushort_t* __restrict__ Vb, ushort_t* __restrict__ Yb) {
  __shared__ __align__(16) ushort_t Ks[2][64 * 64];   // K [t][d], chunk-swizzled
  __shared__ __align__(16) ushort_t Vt[2][64 * 72];   // V^T [d][t], swizzled
  __shared__ __align__(16) ushort_t Pl[8 * 16 * 72];  // per-wave P^T' [q][t], swizzled
  const int id = blockIdx.x;
  const int xcd = id & 7, win = id >> 3;
  const int qt = 15 - (win >> 2);     // longest blocks first
  const int bh = xcd + 8 * (win & 3);
  const int b = bh >> 4, h = bh & 15;
  const int tid = threadIdx.x, w = tid >> 6, lane = tid & 63;
  const int l15 = lane & 15, lhi = lane >> 4;
  const int swzP = 2 * (l15 & 3);
  const size_t base = (size_t)bh * 2048 * 64;
  const float NEG_INF = -__builtin_inff();
  ushort_t* myP = &Pl[w * 16 * 72];

  // K staging: one 16B chunk per thread (512 chunks = 64x64 tile)
  const int krow = tid >> 3, kg = tid & 7;
  const int ksg = kg ^ (krow & 7);
  // V staging: rows t0,t0+1 x 4 d's per thread
  const int vd0 = (tid & 15) * 4;
  const int vt0 = (tid >> 4) * 2;

  const int nkt = 2 * qt + 2;
  const int qrow = w * 16 + l15;  // 0..127 within q-tile

  // Q fragments (B-operand): lane holds Q[q][d = kk*32+lhi*8 ..]
  ushort8 qf[2];
  {
    const size_t qrg = base + (size_t)(qt * 128 + qrow) * 64;
    qf[0] = *(const ushort8*)&Qb[qrg + lhi * 8];
    qf[1] = *(const ushort8*)&Qb[qrg + 32 + lhi * 8];
  }
  float m_s = NEG_INF, l_s = 0.f;
  f32x4 o[4] = {};

  // prologue: stage tile 0 into buf 0
  {
    GLOAD_LDS16(Kb + base + (size_t)krow * 64 + ksg * 8, &Ks[0][tid * 8]);
    const ushort_t* vp = Vb + base + (size_t)vt0 * 64 + vd0;
    u64_t a = *(const u64_t*)vp;
    u64_t c = *(const u64_t*)(vp + 64);
    us4 av = __builtin_bit_cast(us4, a);
    us4 cv = __builtin_bit_cast(us4, c);
#pragma unroll
    for (int i = 0; i < 4; ++i) {
      const int d = vd0 + i;
      const int scg = (vt0 >> 3) ^ ((d >> 3) & 7);
      unsigned int wv = (unsigned int)av[i] | ((unsigned int)cv[i] << 16);
      *(unsigned int*)&Vt[0][d * 72 + scg * 8 + (vt0 & 7)] = wv;
    }
  }
  __syncthreads();

  for (int kt = 0; kt < nkt; ++kt) {
    const int cur = kt & 1, nxt = cur ^ 1;
    const bool pf = (kt + 1 < nkt);
    u64_t va = 0, vc = 0;
    if (pf) {
      const size_t tb = base + (size_t)(kt + 1) * 64 * 64;
      GLOAD_LDS16(Kb + tb + (size_t)krow * 64 + ksg * 8, &Ks[nxt][tid * 8]);
      const ushort_t* vp = Vb + tb + (size_t)vt0 * 64 + vd0;
      va = *(const u64_t*)vp;
      vc = *(const u64_t*)(vp + 64);
    }

    // S^T = mfma(K, Q): s[j] rows t = j*16+lhi*4+r, col q
    f32x4 s[4] = {};
#pragma unroll
    for (int kk = 0; kk < 2; ++kk) {
#pragma unroll
      for (int j = 0; j < 4; ++j) {
        const int g = (kk * 4 + lhi) ^ (l15 & 7);
        ushort8 kb = *(const ushort8*)&Ks[cur][(j * 16 + l15) * 64 + g * 8];
        s[j] = mfma16(kb, qf[kk], s[j]);
      }
    }
    // causal mask; S already in exp2 domain
    if (64 * kt + 63 > 128 * qt + w * 16) {  // wave-uniform: some lane masked
      const int delta = 128 * qt + qrow - 64 * kt;
#pragma unroll
      for (int j = 0; j < 4; ++j)
#pragma unroll
        for (int r = 0; r < 4; ++r)
          if ((j * 16 + lhi * 4 + r) > delta) s[j][r] = NEG_INF;
    }

    // in-lane softmax for q-row (partials across lhi group)
    float pmax = s[0][0];
#pragma unroll
    for (int j = 0; j < 4; ++j)
#pragma unroll
      for (int r = 0; r < 4; ++r) pmax = fmaxf(pmax, s[j][r]);
    pmax = fmaxf(pmax, __shfl_xor(pmax, 16));
    pmax = fmaxf(pmax, __shfl_xor(pmax, 32));
    // defer-max: only rescale when the running max grew by > 8 (P <= 2^8)
    if (__any(pmax - m_s > 8.0f)) {
      const float mnew = fmaxf(m_s, pmax);
      const float al = exp2v(m_s - mnew);
      m_s = mnew;
      l_s *= al;
#pragma unroll
      for (int df = 0; df < 4; ++df)
#pragma unroll
        for (int r = 0; r < 4; ++r) o[df][r] *= al;
    }
    float rsum = 0.f;
#pragma unroll
    for (int j = 0; j < 4; ++j)
#pragma unroll
      for (int r = 0; r < 4; ++r) {
        const float pe = exp2v(s[j][r] - m_s);
        s[j][r] = pe;
        rsum += pe;
      }
    rsum += __shfl_xor(rsum, 16);
    rsum += __shfl_xor(rsum, 32);
    l_s += rsum;

    // P^T pack -> LDS (wave-private, swizzled b64 writes, cvt_pk)
#pragma unroll
    for (int j = 0; j < 4; ++j) {
      const unsigned int w0 = cvtpk(s[j][0], s[j][1]);
      const unsigned int w1 = cvtpk(s[j][2], s[j][3]);
      const u64_t dw = (u64_t)w0 | ((u64_t)w1 << 32);
      const int cg = j * 2 + (lhi >> 1);
      *(u64_t*)&myP[l15 * 72 + ((cg ^ swzP) << 3) + ((lhi & 1) << 2)] = dw;
    }

    // O^T += mfma(V^T-frag, P^T-frag)
#pragma unroll
    for (int kk = 0; kk < 2; ++kk) {
      ushort8 pa = *(const ushort8*)&myP[l15 * 72 + (((kk * 4 + lhi) ^ swzP) << 3)];
#pragma unroll
      for (int df = 0; df < 4; ++df) {
        const int r = df * 16 + l15;
        const int g = (kk * 4 + lhi) ^ ((r >> 3) & 7);
        ushort8 vb = *(const ushort8*)&Vt[cur][r * 72 + g * 8];
        o[df] = mfma16(vb, pa, o[df]);
      }
    }

    // write-late: V^T for next tile
    if (pf) {
      us4 av = __builtin_bit_cast(us4, va);
      us4 cv = __builtin_bit_cast(us4, vc);
#pragma unroll
      for (int i = 0; i < 4; ++i) {
        const int d = vd0 + i;
        const int scg = (vt0 >> 3) ^ ((d >> 3) & 7);
        unsigned int wv = (unsigned int)av[i] | ((unsigned int)cv[i] << 16);
        *(unsigned int*)&Vt[nxt][d * 72 + scg * 8 + (vt0 & 7)] = wv;
      }
    }
    __syncthreads();
  }

  // epilogue: lane holds O^T[d = df*16+lhi*4+r][q]
  const float inv = 1.0f / l_s;
  const size_t yrow = (size_t)(b * 2048 + qt * 128 + qrow) * 1024 + h * 64;
#pragma unroll
  for (int df = 0; df < 4; ++df) {
    us4 ov;
#pragma unroll
    for (int r = 0; r < 4; ++r) ov[r] = f2bf(o[df][r] * inv);
    *(us4*)&Yb[yrow + df * 16 + lhi * 4] = ov;
  }
}

// ---------------- launch ----------------

extern "C" void kernel_launch(void* const* d_in, const int* in_sizes, int n_in,
                              void* d_out, int out_size, void* d_ws, size_t ws_size,
                              hipStream_t stream) {
  const float* x      = (const float*)d_in[0];
  const float* W_kqv  = (const float*)d_in[1];
  const float* b_kqv  = (const float*)d_in[2];
  const float* W_proj = (const float*)d_in[3];
  const float* b_proj = (const float*)d_in[4];
  float* out  = (float*)d_out;          // [B,T,C] fp32
  float* outK = out + 4194304;          // [B,H,T,D] fp32
  float* outV = out + 8388608;          // [B,H,T,D] fp32

  char* ws = (char*)d_ws;
  ushort_t* Xb  = (ushort_t*)(ws);
  ushort_t* Wkt = (ushort_t*)(ws + ((size_t)8 << 20));
  ushort_t* Wpt = (ushort_t*)(ws + ((size_t)14 << 20));
  ushort_t* Qb  = (ushort_t*)(ws + ((size_t)16 << 20));
  ushort_t* Kb  = (ushort_t*)(ws + ((size_t)24 << 20));
  ushort_t* Vb  = (ushort_t*)(ws + ((size_t)32 << 20));
  ushort_t* Yb  = Xb;  // Xb dead after QKV GEMM

  prep_kernel<<<6144, 256, 0, stream>>>(x, W_kqv, W_proj, Xb, Wkt, Wpt);
  gemm_bt_kernel<<<dim3(24, 32), 256, 0, stream>>>(
      Xb, Wkt, b_kqv, nullptr, outK, outV, Qb, Kb, Vb, 4096, 3072, 1024, 1);
  attn_kernel<<<512, 512, 0, stream>>>(Qb, Kb, Vb, Yb);
  gemm_bt64_kernel<<<dim3(8, 64), 256, 0, stream>>>(
      Yb, Wpt, b_proj, out, 4096, 1024, 1024);
}

// Round 16
// 106.701 us; speedup vs baseline: 1.3865x; 1.0197x over previous
//
#include <hip/hip_runtime.h>

// Workspace layout (40 MB total):
//   [0,  8M)  Xb  bf16 [4096][1024]   (reused as Yb after QKV GEMM)
//   [8, 14M)  Wkqv_t bf16 [3072][1024]
//   [14,16M)  Wproj_t bf16 [1024][1024]
//   [16,24M)  Qb bf16 [B,H,T,D]  (pre-scaled by 0.125*log2e)
//   [24,32M)  Kb bf16 [B,H,T,D]
//   [32,40M)  Vb bf16 [B,H,T,D]

#define DEVI __device__ __forceinline__

typedef unsigned short ushort_t;
typedef unsigned long long u64_t;
typedef __attribute__((ext_vector_type(4))) unsigned short us4;
typedef __attribute__((ext_vector_type(8))) unsigned short ushort8;
typedef __attribute__((ext_vector_type(4))) float f32x4;
typedef __attribute__((ext_vector_type(8))) __bf16 bf16x8;

DEVI unsigned short f2bf(float f) {
  union { float f; unsigned int u; } c; c.f = f;
  unsigned int u = c.u;
  unsigned int r = (u + 0x7FFFu + ((u >> 16) & 1u)) >> 16;
  return (unsigned short)r;
}

// exp2 via raw v_exp_f32 (1 VALU trans op; s_nop covers the RAW hazard)
DEVI float exp2v(float x) {
  float r;
  asm("v_exp_f32 %0, %1\n\ts_nop 0" : "=v"(r) : "v"(x));
  return r;
}

// pack 2 fp32 -> 2 bf16 (RNE) in one instruction
DEVI unsigned int cvtpk(float lo, float hi) {
  unsigned int r;
  asm("v_cvt_pk_bf16_f32 %0, %1, %2" : "=v"(r) : "v"(lo), "v"(hi));
  return r;
}

DEVI f32x4 mfma16(ushort8 a, ushort8 b, f32x4 c) {
  return __builtin_amdgcn_mfma_f32_16x16x32_bf16(
      __builtin_bit_cast(bf16x8, a), __builtin_bit_cast(bf16x8, b), c, 0, 0, 0);
}

typedef const __attribute__((address_space(1))) void* gptr_t;
typedef __attribute__((address_space(3))) void* lptr_t;
#define GLOAD_LDS16(g, l) \
  __builtin_amdgcn_global_load_lds((gptr_t)(g), (lptr_t)(l), 16, 0, 0)

DEVI void bar() {
  asm volatile("" ::: "memory");
  __builtin_amdgcn_s_barrier();
  asm volatile("" ::: "memory");
}
#define VMCNT(n) asm volatile("s_waitcnt vmcnt(" #n ")" ::: "memory")

// ---------------- fused prep kernel ----------------
// blocks [0,2048): cast x -> Xb (bf16)
// blocks [2048,5120): transpose+cast W_kqv -> Wkt [3072][1024]
// blocks [5120,6144): transpose+cast W_proj -> Wpt [1024][1024]

__global__ void prep_kernel(const float* __restrict__ x,
                            const float* __restrict__ Wk,
                            const float* __restrict__ Wp,
                            ushort_t* __restrict__ Xb,
                            ushort_t* __restrict__ Wkt,
                            ushort_t* __restrict__ Wpt) {
  __shared__ float tile[32][33];
  const int id = blockIdx.x, tid = threadIdx.x;
  if (id < 2048) {
    const int i = id * 256 + tid;
    const f32x4* p = (const f32x4*)x;
    f32x4 a = p[2 * i], b = p[2 * i + 1];
    ushort8 o;
    o[0] = f2bf(a[0]); o[1] = f2bf(a[1]); o[2] = f2bf(a[2]); o[3] = f2bf(a[3]);
    o[4] = f2bf(b[0]); o[5] = f2bf(b[1]); o[6] = f2bf(b[2]); o[7] = f2bf(b[3]);
    ((ushort8*)Xb)[i] = o;
    return;
  }
  const float* in;
  ushort_t* outp;
  int R = 1024, Cin, bx, by;
  if (id < 5120) {
    const int jid = id - 2048;
    bx = jid % 96; by = jid / 96; in = Wk; outp = Wkt; Cin = 3072;
  } else {
    const int jid = id - 5120;
    bx = jid % 32; by = jid / 32; in = Wp; outp = Wpt; Cin = 1024;
  }
  const int c0 = bx * 32, r0 = by * 32;
  const int tx = tid & 31, ty = tid >> 5;
#pragma unroll
  for (int it = 0; it < 4; ++it)
    tile[ty + it * 8][tx] = in[(size_t)(r0 + ty + it * 8) * Cin + c0 + tx];
  __syncthreads();
#pragma unroll
  for (int it = 0; it < 4; ++it)
    outp[(size_t)(c0 + ty + it * 8) * R + r0 + tx] = f2bf(tile[tx][ty + it * 8]);
}

// ---------------- QKV GEMM: 128x128, m97 structure ----------------
// XCD mapping: by-fast chunked (by = xcd*(nby/8) + idx%(nby/8), bx = idx/(nby/8))
// -> per-XCD working set = (nby/8) A-panels + 1-2 B-panels, L2-resident;
// B read once per XCD instead of once per M-row sweep.

__global__ __launch_bounds__(256) void gemm_bt_kernel(
    const ushort_t* __restrict__ A, const ushort_t* __restrict__ Bt,
    const float* __restrict__ bias, float* __restrict__ outF,
    float* __restrict__ outK, float* __restrict__ outV,
    ushort_t* __restrict__ Qb, ushort_t* __restrict__ Kb, ushort_t* __restrict__ Vb,
    int M, int N, int K, int mode) {
  __shared__ __align__(16) ushort_t As[128 * 64];
  __shared__ __align__(16) ushort_t Bs[128 * 64];
  const int tid = threadIdx.x;
  const int w = tid >> 6, lane = tid & 63;
  const int wr = w >> 1, wc = w & 1;
  // XCD-pinned, by-fast chunked decode (nby % 8 == 0)
  const int nby = gridDim.y;
  const int chy = nby >> 3;
  const int orig = blockIdx.x + gridDim.x * blockIdx.y;
  const int xcd = orig & 7, idx = orig >> 3;
  const int by = xcd * chy + (idx % chy);
  const int bx = idx / chy;
  const int m0 = by * 128, n0 = bx * 128;
  const int l15 = lane & 15, lhi = lane >> 4;
  const int rowA = lane >> 3;
  const int sgc = (((lane & 7) ^ ((lane >> 3) & 7)) << 3);

  f32x4 acc[4][4] = {};

  const int nk = K >> 6;
  for (int kt = 0; kt < nk; ++kt) {
    const size_t k0 = (size_t)kt << 6;
    if (kt) bar();
#pragma unroll
    for (int it = 0; it < 4; ++it) {
      const int rbase = (w * 4 + it) * 8;
      GLOAD_LDS16(A + (size_t)(m0 + rbase + rowA) * K + k0 + sgc, &As[rbase * 64]);
      GLOAD_LDS16(Bt + (size_t)(n0 + rbase + rowA) * K + k0 + sgc, &Bs[rbase * 64]);
    }
    VMCNT(0);
    bar();
#pragma unroll
    for (int kk = 0; kk < 2; ++kk) {
      const int gof = (((kk * 4 + lhi) ^ (l15 & 7)) << 3);
      ushort8 a[4], b[4];
#pragma unroll
      for (int i = 0; i < 4; ++i)
        a[i] = *(const ushort8*)&As[(wr * 64 + i * 16 + l15) * 64 + gof];
#pragma unroll
      for (int j = 0; j < 4; ++j)
        b[j] = *(const ushort8*)&Bs[(wc * 64 + j * 16 + l15) * 64 + gof];
#pragma unroll
      for (int i = 0; i < 4; ++i)
#pragma unroll
        for (int j = 0; j < 4; ++j) acc[i][j] = mfma16(a[i], b[j], acc[i][j]);
    }
  }

  const float QSCALE = 0.18033688011112042f;  // 0.125 * log2(e)
#pragma unroll
  for (int i = 0; i < 4; ++i) {
#pragma unroll
    for (int j = 0; j < 4; ++j) {
      const int nn = n0 + wc * 64 + j * 16 + l15;
      const float bv = bias[nn];
#pragma unroll
      for (int r = 0; r < 4; ++r) {
        const int mm = m0 + wr * 64 + i * 16 + lhi * 4 + r;
        const float v = acc[i][j][r] + bv;
        if (mode == 0) {
          outF[(size_t)mm * N + nn] = v;
        } else {
          const int bb = mm >> 11, t = mm & 2047;
          const int c = nn & 1023, h = c >> 6, d = c & 63;
          const size_t idx2 = ((size_t)(bb * 16 + h) * 2048 + t) * 64 + d;
          const int sec = nn >> 10;
          if (sec == 0) {
            Qb[idx2] = f2bf(v * QSCALE);
          } else if (sec == 1) {
            outK[idx2] = v; Kb[idx2] = f2bf(v);
          } else {
            outV[idx2] = v; Vb[idx2] = f2bf(v);
          }
        }
      }
    }
  }
}

// ---------------- proj GEMM: 64x128 tiles, same chunked XCD mapping ----------------

__global__ __launch_bounds__(256) void gemm_bt64_kernel(
    const ushort_t* __restrict__ A, const ushort_t* __restrict__ Bt,
    const float* __restrict__ bias, float* __restrict__ outF,
    int M, int N, int K) {
  __shared__ __align__(16) ushort_t As[64 * 64];
  __shared__ __align__(16) ushort_t Bs[128 * 64];
  const int tid = threadIdx.x;
  const int w = tid >> 6, lane = tid & 63;
  const int wr = w >> 1, wc = w & 1;
  const int nby = gridDim.y;
  const int chy = nby >> 3;
  const int orig = blockIdx.x + gridDim.x * blockIdx.y;
  const int xcd = orig & 7, idx = orig >> 3;
  const int by = xcd * chy + (idx % chy);
  const int bx = idx / chy;
  const int m0 = by * 64, n0 = bx * 128;
  const int l15 = lane & 15, lhi = lane >> 4;
  const int rowA = lane >> 3;
  const int sgc = (((lane & 7) ^ ((lane >> 3) & 7)) << 3);

  f32x4 acc[2][4] = {};

  const int nk = K >> 6;
  for (int kt = 0; kt < nk; ++kt) {
    const size_t k0 = (size_t)kt << 6;
    if (kt) bar();
#pragma unroll
    for (int it = 0; it < 2; ++it) {
      const int rbase = (w * 2 + it) * 8;  // A: 64 rows
      GLOAD_LDS16(A + (size_t)(m0 + rbase + rowA) * K + k0 + sgc, &As[rbase * 64]);
    }
#pragma unroll
    for (int it = 0; it < 4; ++it) {
      const int rbase = (w * 4 + it) * 8;  // B: 128 rows
      GLOAD_LDS16(Bt + (size_t)(n0 + rbase + rowA) * K + k0 + sgc, &Bs[rbase * 64]);
    }
    VMCNT(0);
    bar();
#pragma unroll
    for (int kk = 0; kk < 2; ++kk) {
      const int gof = (((kk * 4 + lhi) ^ (l15 & 7)) << 3);
      ushort8 a[2], b[4];
#pragma unroll
      for (int i = 0; i < 2; ++i)
        a[i] = *(const ushort8*)&As[(wr * 32 + i * 16 + l15) * 64 + gof];
#pragma unroll
      for (int j = 0; j < 4; ++j)
        b[j] = *(const ushort8*)&Bs[(wc * 64 + j * 16 + l15) * 64 + gof];
#pragma unroll
      for (int i = 0; i < 2; ++i)
#pragma unroll
        for (int j = 0; j < 4; ++j) acc[i][j] = mfma16(a[i], b[j], acc[i][j]);
    }
  }

#pragma unroll
  for (int i = 0; i < 2; ++i) {
#pragma unroll
    for (int j = 0; j < 4; ++j) {
      const int nn = n0 + wc * 64 + j * 16 + l15;
      const float bv = bias[nn];
#pragma unroll
      for (int r = 0; r < 4; ++r) {
        const int mm = m0 + wr * 32 + i * 16 + lhi * 4 + r;
        outF[(size_t)mm * N + nn] = acc[i][j][r] + bv;
      }
    }
  }
}

// ---------------- flash attention: 8 waves, 128-row Q-tile ----------------
// Grid 512 x 512 threads. XCD-pinned (bh%8 == id%8).
// BALANCED-PAIR dispatch: blocks [0,256) carry qt 8..15, blocks [256,512)
// carry qt 7..0, so co-resident pairs (i, i+256) sum to a constant 34 steps
// (was 48 vs 20 with longest-first -> worst-CU tail).

__global__ __launch_bounds__(512) void attn_kernel(
    const ushort_t* __restrict__ Qb, const ushort_t* __restrict__ Kb,
    const ushort_t* __restrict__ Vb, ushort_t* __restrict__ Yb) {
  __shared__ __align__(16) ushort_t Ks[2][64 * 64];   // K [t][d], chunk-swizzled
  __shared__ __align__(16) ushort_t Vt[2][64 * 72];   // V^T [d][t], swizzled
  __shared__ __align__(16) ushort_t Pl[8 * 16 * 72];  // per-wave P^T' [q][t], swizzled
  const int id = blockIdx.x;
  const int xcd = id & 7;
  int qt, bh;
  if (id < 256) {
    const int j = id >> 3;            // 0..31
    bh = xcd + 8 * (j & 3);
    qt = 8 + (j >> 2);                // 8..15 (long halves first)
  } else {
    const int j = (id - 256) >> 3;    // 0..31
    bh = xcd + 8 * (j & 3);
    qt = 7 - (j >> 2);                // 7..0
  }
  const int b = bh >> 4, h = bh & 15;
  const int tid = threadIdx.x, w = tid >> 6, lane = tid & 63;
  const int l15 = lane & 15, lhi = lane >> 4;
  const int swzP = 2 * (l15 & 3);
  const size_t base = (size_t)bh * 2048 * 64;
  const float NEG_INF = -__builtin_inff();
  ushort_t* myP = &Pl[w * 16 * 72];

  // K staging: one 16B chunk per thread (512 chunks = 64x64 tile)
  const int krow = tid >> 3, kg = tid & 7;
  const int ksg = kg ^ (krow & 7);
  // V staging: rows t0,t0+1 x 4 d's per thread
  const int vd0 = (tid & 15) * 4;
  const int vt0 = (tid >> 4) * 2;

  const int nkt = 2 * qt + 2;
  const int qrow = w * 16 + l15;  // 0..127 within q-tile

  // Q fragments (B-operand): lane holds Q[q][d = kk*32+lhi*8 ..]
  ushort8 qf[2];
  {
    const size_t qrg = base + (size_t)(qt * 128 + qrow) * 64;
    qf[0] = *(const ushort8*)&Qb[qrg + lhi * 8];
    qf[1] = *(const ushort8*)&Qb[qrg + 32 + lhi * 8];
  }
  float m_s = NEG_INF, l_s = 0.f;
  f32x4 o[4] = {};

  // prologue: stage tile 0 into buf 0
  {
    GLOAD_LDS16(Kb + base + (size_t)krow * 64 + ksg * 8, &Ks[0][tid * 8]);
    const ushort_t* vp = Vb + base + (size_t)vt0 * 64 + vd0;
    u64_t a = *(const u64_t*)vp;
    u64_t c = *(const u64_t*)(vp + 64);
    us4 av = __builtin_bit_cast(us4, a);
    us4 cv = __builtin_bit_cast(us4, c);
#pragma unroll
    for (int i = 0; i < 4; ++i) {
      const int d = vd0 + i;
      const int scg = (vt0 >> 3) ^ ((d >> 3) & 7);
      unsigned int wv = (unsigned int)av[i] | ((unsigned int)cv[i] << 16);
      *(unsigned int*)&Vt[0][d * 72 + scg * 8 + (vt0 & 7)] = wv;
    }
  }
  __syncthreads();

  for (int kt = 0; kt < nkt; ++kt) {
    const int cur = kt & 1, nxt = cur ^ 1;
    const bool pf = (kt + 1 < nkt);
    u64_t va = 0, vc = 0;
    if (pf) {
      const size_t tb = base + (size_t)(kt + 1) * 64 * 64;
      GLOAD_LDS16(Kb + tb + (size_t)krow * 64 + ksg * 8, &Ks[nxt][tid * 8]);
      const ushort_t* vp = Vb + tb + (size_t)vt0 * 64 + vd0;
      va = *(const u64_t*)vp;
      vc = *(const u64_t*)(vp + 64);
    }

    // S^T = mfma(K, Q): s[j] rows t = j*16+lhi*4+r, col q
    f32x4 s[4] = {};
#pragma unroll
    for (int kk = 0; kk < 2; ++kk) {
#pragma unroll
      for (int j = 0; j < 4; ++j) {
        const int g = (kk * 4 + lhi) ^ (l15 & 7);
        ushort8 kb = *(const ushort8*)&Ks[cur][(j * 16 + l15) * 64 + g * 8];
        s[j] = mfma16(kb, qf[kk], s[j]);
      }
    }
    // causal mask; S already in exp2 domain
    if (64 * kt + 63 > 128 * qt + w * 16) {  // wave-uniform: some lane masked
      const int delta = 128 * qt + qrow - 64 * kt;
#pragma unroll
      for (int j = 0; j < 4; ++j)
#pragma unroll
        for (int r = 0; r < 4; ++r)
          if ((j * 16 + lhi * 4 + r) > delta) s[j][r] = NEG_INF;
    }

    // in-lane softmax for q-row (partials across lhi group)
    float pmax = s[0][0];
#pragma unroll
    for (int j = 0; j < 4; ++j)
#pragma unroll
      for (int r = 0; r < 4; ++r) pmax = fmaxf(pmax, s[j][r]);
    pmax = fmaxf(pmax, __shfl_xor(pmax, 16));
    pmax = fmaxf(pmax, __shfl_xor(pmax, 32));
    // defer-max: only rescale when the running max grew by > 8 (P <= 2^8)
    if (__any(pmax - m_s > 8.0f)) {
      const float mnew = fmaxf(m_s, pmax);
      const float al = exp2v(m_s - mnew);
      m_s = mnew;
      l_s *= al;
#pragma unroll
      for (int df = 0; df < 4; ++df)
#pragma unroll
        for (int r = 0; r < 4; ++r) o[df][r] *= al;
    }
    float rsum = 0.f;
#pragma unroll
    for (int j = 0; j < 4; ++j)
#pragma unroll
      for (int r = 0; r < 4; ++r) {
        const float pe = exp2v(s[j][r] - m_s);
        s[j][r] = pe;
        rsum += pe;
      }
    rsum += __shfl_xor(rsum, 16);
    rsum += __shfl_xor(rsum, 32);
    l_s += rsum;

    // P^T pack -> LDS (wave-private, swizzled b64 writes, cvt_pk)
#pragma unroll
    for (int j = 0; j < 4; ++j) {
      const unsigned int w0 = cvtpk(s[j][0], s[j][1]);
      const unsigned int w1 = cvtpk(s[j][2], s[j][3]);
      const u64_t dw = (u64_t)w0 | ((u64_t)w1 << 32);
      const int cg = j * 2 + (lhi >> 1);
      *(u64_t*)&myP[l15 * 72 + ((cg ^ swzP) << 3) + ((lhi & 1) << 2)] = dw;
    }

    // O^T += mfma(V^T-frag, P^T-frag)
#pragma unroll
    for (int kk = 0; kk < 2; ++kk) {
      ushort8 pa = *(const ushort8*)&myP[l15 * 72 + (((kk * 4 + lhi) ^ swzP) << 3)];
#pragma unroll
      for (int df = 0; df < 4; ++df) {
        const int r = df * 16 + l15;
        const int g = (kk * 4 + lhi) ^ ((r >> 3) & 7);
        ushort8 vb = *(const ushort8*)&Vt[cur][r * 72 + g * 8];
        o[df] = mfma16(vb, pa, o[df]);
      }
    }

    // write-late: V^T for next tile
    if (pf) {
      us4 av = __builtin_bit_cast(us4, va);
      us4 cv = __builtin_bit_cast(us4, vc);
#pragma unroll
      for (int i = 0; i < 4; ++i) {
        const int d = vd0 + i;
        const int scg = (vt0 >> 3) ^ ((d >> 3) & 7);
        unsigned int wv = (unsigned int)av[i] | ((unsigned int)cv[i] << 16);
        *(unsigned int*)&Vt[nxt][d * 72 + scg * 8 + (vt0 & 7)] = wv;
      }
    }
    __syncthreads();
  }

  // epilogue: lane holds O^T[d = df*16+lhi*4+r][q]
  const float inv = 1.0f / l_s;
  const size_t yrow = (size_t)(b * 2048 + qt * 128 + qrow) * 1024 + h * 64;
#pragma unroll
  for (int df = 0; df < 4; ++df) {
    us4 ov;
#pragma unroll
    for (int r = 0; r < 4; ++r) ov[r] = f2bf(o[df][r] * inv);
    *(us4*)&Yb[yrow + df * 16 + lhi * 4] = ov;
  }
}

// ---------------- launch ----------------

extern "C" void kernel_launch(void* const* d_in, const int* in_sizes, int n_in,
                              void* d_out, int out_size, void* d_ws, size_t ws_size,
                              hipStream_t stream) {
  const float* x      = (const float*)d_in[0];
  const float* W_kqv  = (const float*)d_in[1];
  const float* b_kqv  = (const float*)d_in[2];
  const float* W_proj = (const float*)d_in[3];
  const float* b_proj = (const float*)d_in[4];
  float* out  = (float*)d_out;          // [B,T,C] fp32
  float* outK = out + 4194304;          // [B,H,T,D] fp32
  float* outV = out + 8388608;          // [B,H,T,D] fp32

  char* ws = (char*)d_ws;
  ushort_t* Xb  = (ushort_t*)(ws);
  ushort_t* Wkt = (ushort_t*)(ws + ((size_t)8 << 20));
  ushort_t* Wpt = (ushort_t*)(ws + ((size_t)14 << 20));
  ushort_t* Qb  = (ushort_t*)(ws + ((size_t)16 << 20));
  ushort_t* Kb  = (ushort_t*)(ws + ((size_t)24 << 20));
  ushort_t* Vb  = (ushort_t*)(ws + ((size_t)32 << 20));
  ushort_t* Yb  = Xb;  // Xb dead after QKV GEMM

  prep_kernel<<<6144, 256, 0, stream>>>(x, W_kqv, W_proj, Xb, Wkt, Wpt);
  gemm_bt_kernel<<<dim3(24, 32), 256, 0, stream>>>(
      Xb, Wkt, b_kqv, nullptr, outK, outV, Qb, Kb, Vb, 4096, 3072, 1024, 1);
  attn_kernel<<<512, 512, 0, stream>>>(Qb, Kb, Vb, Yb);
  gemm_bt64_kernel<<<dim3(8, 64), 256, 0, stream>>>(
      Yb, Wpt, b_proj, out, 4096, 1024, 1024);
}